// Round 4
// baseline (249.988 us; speedup 1.0000x reference)
//
#include <hip/hip_runtime.h>
#include <hip/hip_bf16.h>

// Problem constants (fixed by setup_inputs)
#define B_ 16
#define N_ 2048
#define C_ 64
#define E_ 16
#define O_ 64
#define H_ 16

typedef __attribute__((ext_vector_type(8)))  short short8;   // 8 bf16 (MFMA A/B frag)
typedef __attribute__((ext_vector_type(16))) float f32x16;   // MFMA C/D frag

// Workspace layout (float offsets). Total 7,667,712 floats = 30.7 MB.
#define NVB_OFF  0u        // nodevec bf16 [B][N][E]   524288 bf16 = 262144 f
#define RSP_OFF  262144u   // rowsum  f32  [2][B][N]   65536 f
#define XST_OFF  327680u   // xs^T    bf16 [B][C][N]   2097152 bf16 = 1048576 f
#define YT_OFF   1376256u  // A@xs    f32  [2][B][C][N] 4194304 f
#define XG2T_OFF 5570560u  // x_g2^T  f32  [B][C][N]   2097152 f

__device__ __forceinline__ unsigned short f2bf(float f) {
  union { float f; unsigned int u; } v; v.f = f;
  unsigned int r = v.u + 0x7FFFu + ((v.u >> 16) & 1u);   // RNE
  return (unsigned short)(r >> 16);
}

#define CVT_PK(dst, lo_, hi_) \
  asm("v_cvt_pk_bf16_f32 %0, %1, %2" : "=v"(dst) : "v"(lo_), "v"(hi_))
#define PL_SWAP(x_, y_) \
  asm("v_permlane32_swap_b32 %0, %1" : "+v"(x_), "+v"(y_))

// ---------------------------------------------------------------------------
// K1: hypernet MLP + nodevec = tanh(emb0 * filt), written as bf16.
// One thread per (b,n). grid 128 x 256.
// ---------------------------------------------------------------------------
__global__ __launch_bounds__(256) void k1_hyper(
    const float* __restrict__ x, const float* __restrict__ emb0,
    const float* __restrict__ w1, const float* __restrict__ b1,
    const float* __restrict__ w2, const float* __restrict__ b2,
    const float* __restrict__ w3, const float* __restrict__ b3,
    unsigned short* __restrict__ nvb)
{
  __shared__ float w1s[C_*H_];
  __shared__ float b1s[H_], w2s[H_*2], b2s[2], w3s[2*E_], b3s[E_];
  int tid = threadIdx.x;
  for (int i = tid; i < C_*H_; i += 256) w1s[i] = w1[i];
  if (tid < H_)   b1s[tid] = b1[tid];
  if (tid < H_*2) w2s[tid] = w2[tid];
  if (tid < 2)    b2s[tid] = b2[tid];
  if (tid < 2*E_) w3s[tid] = w3[tid];
  if (tid < E_)   b3s[tid] = b3[tid];
  __syncthreads();

  int idx = blockIdx.x * 256 + tid;  // b*N + n
  float xr[C_];
  const float4* xp = reinterpret_cast<const float4*>(x + (size_t)idx * C_);
  #pragma unroll
  for (int j = 0; j < 16; ++j) {
    float4 v = xp[j];
    xr[4*j] = v.x; xr[4*j+1] = v.y; xr[4*j+2] = v.z; xr[4*j+3] = v.w;
  }
  float h1[H_];
  #pragma unroll
  for (int h = 0; h < H_; ++h) h1[h] = b1s[h];
  #pragma unroll 8
  for (int c = 0; c < C_; ++c) {
    float xv = xr[c];
    #pragma unroll
    for (int j = 0; j < 4; ++j) {
      float4 w = reinterpret_cast<const float4*>(&w1s[c*H_])[j];
      h1[4*j]   = fmaf(xv, w.x, h1[4*j]);
      h1[4*j+1] = fmaf(xv, w.y, h1[4*j+1]);
      h1[4*j+2] = fmaf(xv, w.z, h1[4*j+2]);
      h1[4*j+3] = fmaf(xv, w.w, h1[4*j+3]);
    }
  }
  #pragma unroll
  for (int h = 0; h < H_; ++h) h1[h] = 1.f / (1.f + __expf(-h1[h]));
  float a0 = b2s[0], a1 = b2s[1];
  #pragma unroll
  for (int h = 0; h < H_; ++h) {
    a0 = fmaf(h1[h], w2s[h*2],   a0);
    a1 = fmaf(h1[h], w2s[h*2+1], a1);
  }
  a0 = 1.f / (1.f + __expf(-a0));
  a1 = 1.f / (1.f + __expf(-a1));

  const float4* ep = reinterpret_cast<const float4*>(emb0 + (size_t)idx * E_);
  unsigned short us[E_];
  #pragma unroll
  for (int j = 0; j < 4; ++j) {
    float4 e = ep[j];
    int c = 4*j;
    us[c]   = f2bf(tanhf(e.x * (b3s[c]   + a0*w3s[c]   + a1*w3s[E_+c])));
    us[c+1] = f2bf(tanhf(e.y * (b3s[c+1] + a0*w3s[c+1] + a1*w3s[E_+c+1])));
    us[c+2] = f2bf(tanhf(e.z * (b3s[c+2] + a0*w3s[c+2] + a1*w3s[E_+c+2])));
    us[c+3] = f2bf(tanhf(e.w * (b3s[c+3] + a0*w3s[c+3] + a1*w3s[E_+c+3])));
  }
  // two 16B stores (row is 32B)
  *reinterpret_cast<short8*>(nvb + (size_t)idx * E_)     = *reinterpret_cast<short8*>(&us[0]);
  *reinterpret_cast<short8*>(nvb + (size_t)idx * E_ + 8) = *reinterpret_cast<short8*>(&us[8]);
}

// ---------------------------------------------------------------------------
// P1: rowsum partials via MFMA. Swapped QK^T: D[i][j] = S(m0+i, N0+j);
// lane owns n = N0+(lane&31); regs cover 16 of 32 m per chunk, partner the rest.
// grid 512 (xcd-swizzled) x 256. Each wave: 32-row n-tile, m-half = 1024.
// ---------------------------------------------------------------------------
__global__ __launch_bounds__(256) void p1_rowsum(
    const unsigned short* __restrict__ nvb, float* __restrict__ rsp)
{
  int tid = threadIdx.x, lane = tid & 63, wid = tid >> 6;
  int lo = lane & 31, hi = lane >> 5;
  int orig = blockIdx.x;
  int eff = (orig & 7) * 64 + (orig >> 3);       // bijective XCD swizzle (512 = 8*64)
  int rb = eff & 15, b = (eff >> 4) & 15, part = eff >> 8;
  int N0 = rb * 128 + wid * 32;

  short8 bfrag = *reinterpret_cast<const short8*>(
      nvb + ((size_t)b * N_ + N0 + lo) * E_ + 8 * hi);
  f32x16 zero = {};
  float rs = 0.f;
  const unsigned short* abase =
      nvb + ((size_t)b * N_ + part * 1024 + lo) * E_ + 8 * hi;
  #pragma unroll 2
  for (int mc = 0; mc < 32; ++mc) {
    short8 afrag = *reinterpret_cast<const short8*>(abase + (size_t)mc * 32 * E_);
    f32x16 p = __builtin_amdgcn_mfma_f32_32x32x16_bf16(afrag, bfrag, zero, 0, 0, 0);
    #pragma unroll
    for (int r = 0; r < 16; ++r) rs += fmaxf(p[r], 0.f);
  }
  rs += __shfl_xor(rs, 32, 64);
  if (lane < 32) rsp[((size_t)part * B_ + b) * N_ + N0 + lo] = rs;
}

// ---------------------------------------------------------------------------
// P2: xs^T[b][c][m] = bf16( d_m * x[b][m][c] ).  d_m = rsqrt(rs0+rs1).
// grid (16 m-super, 16 b) x 256. thread = (c = tid&63, g = tid>>6); 32 m each.
// x reads coalesced (64 consecutive c per wave per m-step); 64B store/thread.
// ---------------------------------------------------------------------------
__global__ __launch_bounds__(256) void p2_scaleT(
    const float* __restrict__ x, const float* __restrict__ rsp,
    unsigned short* __restrict__ xsT)
{
  int tid = threadIdx.x;
  int c = tid & 63, g = tid >> 6;
  int m0 = blockIdx.x * 128 + g * 32;
  int b  = blockIdx.y;
  const float* rp = rsp + (size_t)b * N_;
  unsigned int pk[16];
  #pragma unroll
  for (int k = 0; k < 32; ++k) {
    int m = m0 + k;
    float d = rsqrtf(rp[m] + rp[(size_t)B_ * N_ + m]);
    float v = d * x[((size_t)b * N_ + m) * C_ + c];
    unsigned short us = f2bf(v);
    if (k & 1) pk[k >> 1] |= ((unsigned int)us) << 16;
    else       pk[k >> 1]  = us;
  }
  unsigned short* o = xsT + ((size_t)b * C_ + c) * N_ + m0;
  #pragma unroll
  for (int j = 0; j < 4; ++j)
    reinterpret_cast<uint4*>(o)[j] = *reinterpret_cast<uint4*>(&pk[4*j]);
}

// ---------------------------------------------------------------------------
// P3: y^T[part][b][c][n] = sum_{m in half} relu(nv_n . nv_m) * xs[m][c]
// Swapped QK^T tile (lane owns n), relu in f32 regs, cvt_pk_bf16 +
// permlane32_swap assemble P as the PV B-operand; xs^T rows are the PV
// A-operand (single 16B loads). 5 MFMA / 32-m chunk. grid 512 x 256.
// ---------------------------------------------------------------------------
__global__ __launch_bounds__(256) void p3_spmm(
    const unsigned short* __restrict__ nvb, const unsigned short* __restrict__ xsT,
    float* __restrict__ yT)
{
  int tid = threadIdx.x, lane = tid & 63, wid = tid >> 6;
  int lo = lane & 31, hi = lane >> 5;
  int orig = blockIdx.x;
  int eff = (orig & 7) * 64 + (orig >> 3);
  int rb = eff & 15, b = (eff >> 4) & 15, part = eff >> 8;
  int N0 = rb * 128 + wid * 32;

  short8 bfrag = *reinterpret_cast<const short8*>(
      nvb + ((size_t)b * N_ + N0 + lo) * E_ + 8 * hi);
  f32x16 acc0 = {}, acc1 = {};
  f32x16 zero = {};
  const unsigned short* abase =
      nvb + ((size_t)b * N_ + part * 1024 + lo) * E_ + 8 * hi;
  const unsigned short* xb0 = xsT + ((size_t)b * C_ + lo) * N_ + part * 1024 + 8 * hi;
  const unsigned short* xb1 = xb0 + (size_t)32 * N_;

  #pragma unroll 2
  for (int mc = 0; mc < 32; ++mc) {
    int mo = mc * 32;
    short8 afrag = *reinterpret_cast<const short8*>(abase + (size_t)mo * E_);
    // PV A-frags (xs^T) — independent of S, issue early
    short8 x00 = *reinterpret_cast<const short8*>(xb0 + mo);
    short8 x01 = *reinterpret_cast<const short8*>(xb0 + mo + 16);
    short8 x10 = *reinterpret_cast<const short8*>(xb1 + mo);
    short8 x11 = *reinterpret_cast<const short8*>(xb1 + mo + 16);

    f32x16 p = __builtin_amdgcn_mfma_f32_32x32x16_bf16(afrag, bfrag, zero, 0, 0, 0);
    float q[16];
    #pragma unroll
    for (int r = 0; r < 16; ++r) q[r] = fmaxf(p[r], 0.f);

    unsigned int A0, Bb0, C0, D0, A1, Bb1, C1, D1;
    CVT_PK(A0,  q[0],  q[1]);  CVT_PK(Bb0, q[2],  q[3]);
    CVT_PK(C0,  q[4],  q[5]);  CVT_PK(D0,  q[6],  q[7]);
    CVT_PK(A1,  q[8],  q[9]);  CVT_PK(Bb1, q[10], q[11]);
    CVT_PK(C1,  q[12], q[13]); CVT_PK(D1,  q[14], q[15]);
    PL_SWAP(A0, C0);  PL_SWAP(Bb0, D0);   // {A0,Bb0,C0,D0} = P-frag k-group 0
    PL_SWAP(A1, C1);  PL_SWAP(Bb1, D1);   // {A1,Bb1,C1,D1} = P-frag k-group 1

    union { unsigned int u[4]; short8 s; } f0, f1;
    f0.u[0] = A0; f0.u[1] = Bb0; f0.u[2] = C0; f0.u[3] = D0;
    f1.u[0] = A1; f1.u[1] = Bb1; f1.u[2] = C1; f1.u[3] = D1;

    acc0 = __builtin_amdgcn_mfma_f32_32x32x16_bf16(x00, f0.s, acc0, 0, 0, 0);
    acc0 = __builtin_amdgcn_mfma_f32_32x32x16_bf16(x01, f1.s, acc0, 0, 0, 0);
    acc1 = __builtin_amdgcn_mfma_f32_32x32x16_bf16(x10, f0.s, acc1, 0, 0, 0);
    acc1 = __builtin_amdgcn_mfma_f32_32x32x16_bf16(x11, f1.s, acc1, 0, 0, 0);
  }

  float* yb = yT + ((size_t)part * B_ + b) * C_ * N_;
  #pragma unroll
  for (int r = 0; r < 16; ++r) {
    int cl = (r & 3) + 8 * (r >> 2) + 4 * hi;       // verified C/D row mapping
    yb[(size_t)cl * N_ + N0 + lo]        = acc0[r];
    yb[(size_t)(cl + 32) * N_ + N0 + lo] = acc1[r];
  }
}

// ---------------------------------------------------------------------------
// P4: xg2^T[b][c][n] = d_n * (y0 + y1). grid (8 n-tiles, 64 c, 16 b) x 256.
// ---------------------------------------------------------------------------
__global__ __launch_bounds__(256) void p4_reduce(
    const float* __restrict__ yT, const float* __restrict__ rsp,
    float* __restrict__ xg2T)
{
  int n = blockIdx.x * 256 + threadIdx.x;
  int c = blockIdx.y, b = blockIdx.z;
  float rs = rsp[(size_t)b * N_ + n] + rsp[(size_t)B_ * N_ + (size_t)b * N_ + n];
  float d = rsqrtf(rs);
  size_t o = ((size_t)b * C_ + c) * N_ + n;
  float y = yT[o] + yT[(size_t)B_ * C_ * N_ + o];
  xg2T[o] = d * y;
}

// ---------------------------------------------------------------------------
// K4: out[b,n,o] = sum_ki x_g[b,n,ki] * (sum_d emb1[n,d] wp[d,ki,o]) + bias.
// lane=o. Wave handles 4 nodes x 8 batches. xg2 now transposed [b][c][n].
// ---------------------------------------------------------------------------
__global__ __launch_bounds__(256) void k4_out(
    const float* __restrict__ x, const float* __restrict__ xg2T,
    const float* __restrict__ emb1, const float* __restrict__ wp,
    const float* __restrict__ bp, float* __restrict__ out)
{
  int tid  = threadIdx.x;
  int lane = tid & 63;
  int wid  = tid >> 6;
  int gw   = blockIdx.x * 4 + wid;  // 0..1023
  int n0   = (gw >> 1) * 4;
  int b0   = (gw & 1) * 8;

  float e1[4][E_];
  #pragma unroll
  for (int nn = 0; nn < 4; ++nn)
    #pragma unroll
    for (int d = 0; d < E_; ++d) e1[nn][d] = emb1[(n0+nn)*E_ + d];

  float acc[4][8];
  #pragma unroll
  for (int nn = 0; nn < 4; ++nn)
    #pragma unroll
    for (int bb = 0; bb < 8; ++bb) acc[nn][bb] = 0.f;

  for (int kp = 0; kp < 64; ++kp) {
    int ki0 = kp * 2;
    float w0[4] = {0,0,0,0}, w1v[4] = {0,0,0,0};
    #pragma unroll
    for (int d = 0; d < E_; ++d) {
      float p0 = wp[((size_t)d*128 + ki0)     * 64 + lane];
      float p1 = wp[((size_t)d*128 + ki0 + 1) * 64 + lane];
      #pragma unroll
      for (int nn = 0; nn < 4; ++nn) {
        w0[nn]  = fmaf(e1[nn][d], p0, w0[nn]);
        w1v[nn] = fmaf(e1[nn][d], p1, w1v[nn]);
      }
    }
    if (ki0 < 64) {
      #pragma unroll
      for (int nn = 0; nn < 4; ++nn)
        #pragma unroll
        for (int bb = 0; bb < 8; ++bb) {
          const float* p = x + (((size_t)(b0+bb) * N_) + (n0+nn)) * C_ + ki0;
          acc[nn][bb] = fmaf(p[0], w0[nn], fmaf(p[1], w1v[nn], acc[nn][bb]));
        }
    } else {
      int koff = ki0 - 64;
      #pragma unroll
      for (int nn = 0; nn < 4; ++nn)
        #pragma unroll
        for (int bb = 0; bb < 8; ++bb) {
          const float* p = xg2T + ((size_t)(b0+bb) * C_ + koff) * N_ + (n0+nn);
          acc[nn][bb] = fmaf(p[0], w0[nn], fmaf(p[N_], w1v[nn], acc[nn][bb]));
        }
    }
  }
  #pragma unroll
  for (int nn = 0; nn < 4; ++nn) {
    float bias = 0.f;
    #pragma unroll
    for (int d = 0; d < E_; ++d) bias = fmaf(e1[nn][d], bp[d*O_ + lane], bias);
    #pragma unroll
    for (int bb = 0; bb < 8; ++bb)
      out[(((size_t)(b0+bb) * N_) + (n0+nn)) * O_ + lane] = acc[nn][bb] + bias;
  }
}

// ---------------------------------------------------------------------------
extern "C" void kernel_launch(void* const* d_in, const int* in_sizes, int n_in,
                              void* d_out, int out_size, void* d_ws, size_t ws_size,
                              hipStream_t stream)
{
  const float* x    = (const float*)d_in[0];
  const float* emb0 = (const float*)d_in[1];
  const float* emb1 = (const float*)d_in[2];
  const float* w1   = (const float*)d_in[3];
  const float* b1   = (const float*)d_in[4];
  const float* w2   = (const float*)d_in[5];
  const float* b2   = (const float*)d_in[6];
  const float* w3   = (const float*)d_in[7];
  const float* b3   = (const float*)d_in[8];
  const float* wp   = (const float*)d_in[9];
  const float* bp   = (const float*)d_in[10];
  float* out = (float*)d_out;
  float* ws  = (float*)d_ws;   // needs ~30.7 MB

  unsigned short* nvb = (unsigned short*)(ws + NVB_OFF);
  float*          rsp = ws + RSP_OFF;
  unsigned short* xsT = (unsigned short*)(ws + XST_OFF);
  float*          yT  = ws + YT_OFF;
  float*          xg2T= ws + XG2T_OFF;

  k1_hyper <<<128, 256, 0, stream>>>(x, emb0, w1, b1, w2, b2, w3, b3, nvb);
  p1_rowsum<<<512, 256, 0, stream>>>(nvb, rsp);
  p2_scaleT<<<dim3(16,16), 256, 0, stream>>>(x, rsp, xsT);
  p3_spmm  <<<512, 256, 0, stream>>>(nvb, xsT, yT);
  p4_reduce<<<dim3(8,64,16), 256, 0, stream>>>(yT, rsp, xg2T);
  k4_out   <<<256, 256, 0, stream>>>(x, xg2T, emb1, wp, bp, out);
}

// Round 9
// 185.837 us; speedup vs baseline: 1.3452x; 1.3452x over previous
//
#include <hip/hip_runtime.h>
#include <hip/hip_bf16.h>

// Problem constants (fixed by setup_inputs)
#define B_ 16
#define N_ 2048
#define C_ 64
#define E_ 16
#define O_ 64
#define H_ 16

typedef __attribute__((ext_vector_type(8)))  short short8;   // 8 bf16 (MFMA A/B frag)
typedef __attribute__((ext_vector_type(16))) float f32x16;   // MFMA C/D frag

// Workspace layout (float offsets). Total 7,750,144 floats = 31.0 MB.
#define NVB_OFF   0u        // nodevec bf16 [B][N][E]    524288 bf16 = 262144 f
#define RSP_OFF   262144u   // rowsum  f32  [2][B][N]    65536 f
#define XST_OFF   327680u   // xs^T    bf16 [B][C][N]    2097152 bf16 = 1048576 f
#define YT_OFF    1376256u  // A@xs    f32  [2][B][C][N] 4194304 f
#define XGALL_OFF 5570560u  // xg bf16 [B][N][128] (x | xg2)  4194304 bf16 = 2097152 f
#define WPB_OFF   7667712u  // wpB bf16 frag-ordered, 129 kc * 2 * 64 * 8 = 132096 bf16
#define E1B_OFF   7733760u  // emb1 bf16 [N][16] = 32768 bf16 = 16384 f

__device__ __forceinline__ unsigned short f2bf(float f) {
  union { float f; unsigned int u; } v; v.f = f;
  unsigned int r = v.u + 0x7FFFu + ((v.u >> 16) & 1u);   // RNE
  return (unsigned short)(r >> 16);
}

#define CVT_PK(dst, lo_, hi_) \
  asm("v_cvt_pk_bf16_f32 %0, %1, %2" : "=v"(dst) : "v"(lo_), "v"(hi_))
#define PL_SWAP(x_, y_) \
  asm("v_permlane32_swap_b32 %0, %1" : "+v"(x_), "+v"(y_))

// ---------------------------------------------------------------------------
// K0: prep wpB (fragment-ordered bf16 of weights_pool + bias chunk) and
// emb1 bf16. wpB[kc][sub][o][t]: kc<128 -> wp[q=kc*16+sub*8+t][o];
// kc==128 -> bp[sub*8+t][o]. grid 644 x 256 (exactly 164864 elements).
// ---------------------------------------------------------------------------
__global__ __launch_bounds__(256) void k0_prep(
    const float* __restrict__ wp, const float* __restrict__ bp,
    const float* __restrict__ emb1,
    unsigned short* __restrict__ wpB, unsigned short* __restrict__ emb1b)
{
  int id = blockIdx.x * 256 + threadIdx.x;
  if (id < 132096) {
    int t = id & 7, o = (id >> 3) & 63, rest = id >> 9;
    int sub = rest & 1, kc = rest >> 1;
    int q2 = sub * 8 + t;
    float v = (kc < 128) ? wp[(size_t)(kc * 16 + q2) * 64 + o]
                         : bp[(size_t)q2 * 64 + o];
    wpB[id] = f2bf(v);
  } else {
    int id2 = id - 132096;   // < 32768
    emb1b[id2] = f2bf(emb1[id2]);
  }
}

// ---------------------------------------------------------------------------
// K1: hypernet MLP + nodevec = tanh(emb0 * filt) -> bf16; also emits the
// x-row as bf16 into xgall[:, 0:64]. One thread per (b,n). grid 128 x 256.
// ---------------------------------------------------------------------------
__global__ __launch_bounds__(256) void k1_hyper(
    const float* __restrict__ x, const float* __restrict__ emb0,
    const float* __restrict__ w1, const float* __restrict__ b1,
    const float* __restrict__ w2, const float* __restrict__ b2,
    const float* __restrict__ w3, const float* __restrict__ b3,
    unsigned short* __restrict__ nvb, unsigned short* __restrict__ xgall)
{
  __shared__ float w1s[C_*H_];
  __shared__ float b1s[H_], w2s[H_*2], b2s[2], w3s[2*E_], b3s[E_];
  int tid = threadIdx.x;
  for (int i = tid; i < C_*H_; i += 256) w1s[i] = w1[i];
  if (tid < H_)   b1s[tid] = b1[tid];
  if (tid < H_*2) w2s[tid] = w2[tid];
  if (tid < 2)    b2s[tid] = b2[tid];
  if (tid < 2*E_) w3s[tid] = w3[tid];
  if (tid < E_)   b3s[tid] = b3[tid];
  __syncthreads();

  int idx = blockIdx.x * 256 + tid;  // b*N + n
  float xr[C_];
  const float4* xp = reinterpret_cast<const float4*>(x + (size_t)idx * C_);
  #pragma unroll
  for (int j = 0; j < 16; ++j) {
    float4 v = xp[j];
    xr[4*j] = v.x; xr[4*j+1] = v.y; xr[4*j+2] = v.z; xr[4*j+3] = v.w;
  }
  // x row -> bf16 into xgall[idx][0:64]  (64 shorts = 8 x uint4)
  unsigned short xus[C_];
  #pragma unroll
  for (int c = 0; c < C_; ++c) xus[c] = f2bf(xr[c]);
  unsigned short* xo = xgall + (size_t)idx * 128;
  #pragma unroll
  for (int j = 0; j < 8; ++j)
    reinterpret_cast<uint4*>(xo)[j] = reinterpret_cast<uint4*>(xus)[j];

  float h1[H_];
  #pragma unroll
  for (int h = 0; h < H_; ++h) h1[h] = b1s[h];
  #pragma unroll 8
  for (int c = 0; c < C_; ++c) {
    float xv = xr[c];
    #pragma unroll
    for (int j = 0; j < 4; ++j) {
      float4 w = reinterpret_cast<const float4*>(&w1s[c*H_])[j];
      h1[4*j]   = fmaf(xv, w.x, h1[4*j]);
      h1[4*j+1] = fmaf(xv, w.y, h1[4*j+1]);
      h1[4*j+2] = fmaf(xv, w.z, h1[4*j+2]);
      h1[4*j+3] = fmaf(xv, w.w, h1[4*j+3]);
    }
  }
  #pragma unroll
  for (int h = 0; h < H_; ++h) h1[h] = 1.f / (1.f + __expf(-h1[h]));
  float a0 = b2s[0], a1 = b2s[1];
  #pragma unroll
  for (int h = 0; h < H_; ++h) {
    a0 = fmaf(h1[h], w2s[h*2],   a0);
    a1 = fmaf(h1[h], w2s[h*2+1], a1);
  }
  a0 = 1.f / (1.f + __expf(-a0));
  a1 = 1.f / (1.f + __expf(-a1));

  const float4* ep = reinterpret_cast<const float4*>(emb0 + (size_t)idx * E_);
  unsigned short us[E_];
  #pragma unroll
  for (int j = 0; j < 4; ++j) {
    float4 e = ep[j];
    int c = 4*j;
    us[c]   = f2bf(tanhf(e.x * (b3s[c]   + a0*w3s[c]   + a1*w3s[E_+c])));
    us[c+1] = f2bf(tanhf(e.y * (b3s[c+1] + a0*w3s[c+1] + a1*w3s[E_+c+1])));
    us[c+2] = f2bf(tanhf(e.z * (b3s[c+2] + a0*w3s[c+2] + a1*w3s[E_+c+2])));
    us[c+3] = f2bf(tanhf(e.w * (b3s[c+3] + a0*w3s[c+3] + a1*w3s[E_+c+3])));
  }
  *reinterpret_cast<short8*>(nvb + (size_t)idx * E_)     = *reinterpret_cast<short8*>(&us[0]);
  *reinterpret_cast<short8*>(nvb + (size_t)idx * E_ + 8) = *reinterpret_cast<short8*>(&us[8]);
}

// ---------------------------------------------------------------------------
// P1: rowsum partials via MFMA (swapped QK^T, lane owns n). grid 512 x 256.
// ---------------------------------------------------------------------------
__global__ __launch_bounds__(256) void p1_rowsum(
    const unsigned short* __restrict__ nvb, float* __restrict__ rsp)
{
  int tid = threadIdx.x, lane = tid & 63, wid = tid >> 6;
  int lo = lane & 31, hi = lane >> 5;
  int orig = blockIdx.x;
  int eff = (orig & 7) * 64 + (orig >> 3);       // bijective XCD swizzle (512 = 8*64)
  int rb = eff & 15, b = (eff >> 4) & 15, part = eff >> 8;
  int N0 = rb * 128 + wid * 32;

  short8 bfrag = *reinterpret_cast<const short8*>(
      nvb + ((size_t)b * N_ + N0 + lo) * E_ + 8 * hi);
  f32x16 zero = {};
  float rs = 0.f;
  const unsigned short* abase =
      nvb + ((size_t)b * N_ + part * 1024 + lo) * E_ + 8 * hi;
  #pragma unroll 2
  for (int mc = 0; mc < 32; ++mc) {
    short8 afrag = *reinterpret_cast<const short8*>(abase + (size_t)mc * 32 * E_);
    f32x16 p = __builtin_amdgcn_mfma_f32_32x32x16_bf16(afrag, bfrag, zero, 0, 0, 0);
    #pragma unroll
    for (int r = 0; r < 16; ++r) rs += fmaxf(p[r], 0.f);
  }
  rs += __shfl_xor(rs, 32, 64);
  if (lane < 32) rsp[((size_t)part * B_ + b) * N_ + N0 + lo] = rs;
}

// ---------------------------------------------------------------------------
// P2: xs^T[b][c][m] = bf16( d_m * x[b][m][c] ). grid (16,16) x 256.
// ---------------------------------------------------------------------------
__global__ __launch_bounds__(256) void p2_scaleT(
    const float* __restrict__ x, const float* __restrict__ rsp,
    unsigned short* __restrict__ xsT)
{
  int tid = threadIdx.x;
  int c = tid & 63, g = tid >> 6;
  int m0 = blockIdx.x * 128 + g * 32;
  int b  = blockIdx.y;
  const float* rp = rsp + (size_t)b * N_;
  unsigned int pk[16];
  #pragma unroll
  for (int k = 0; k < 32; ++k) {
    int m = m0 + k;
    float d = rsqrtf(rp[m] + rp[(size_t)B_ * N_ + m]);
    float v = d * x[((size_t)b * N_ + m) * C_ + c];
    unsigned short us = f2bf(v);
    if (k & 1) pk[k >> 1] |= ((unsigned int)us) << 16;
    else       pk[k >> 1]  = us;
  }
  unsigned short* o = xsT + ((size_t)b * C_ + c) * N_ + m0;
  #pragma unroll
  for (int j = 0; j < 4; ++j)
    reinterpret_cast<uint4*>(o)[j] = *reinterpret_cast<uint4*>(&pk[4*j]);
}

// ---------------------------------------------------------------------------
// P3: y^T[part][b][c][n] = sum_m relu(nv_n . nv_m) * xs[m][c]. grid 512 x 256.
// ---------------------------------------------------------------------------
__global__ __launch_bounds__(256) void p3_spmm(
    const unsigned short* __restrict__ nvb, const unsigned short* __restrict__ xsT,
    float* __restrict__ yT)
{
  int tid = threadIdx.x, lane = tid & 63, wid = tid >> 6;
  int lo = lane & 31, hi = lane >> 5;
  int orig = blockIdx.x;
  int eff = (orig & 7) * 64 + (orig >> 3);
  int rb = eff & 15, b = (eff >> 4) & 15, part = eff >> 8;
  int N0 = rb * 128 + wid * 32;

  short8 bfrag = *reinterpret_cast<const short8*>(
      nvb + ((size_t)b * N_ + N0 + lo) * E_ + 8 * hi);
  f32x16 acc0 = {}, acc1 = {};
  f32x16 zero = {};
  const unsigned short* abase =
      nvb + ((size_t)b * N_ + part * 1024 + lo) * E_ + 8 * hi;
  const unsigned short* xb0 = xsT + ((size_t)b * C_ + lo) * N_ + part * 1024 + 8 * hi;
  const unsigned short* xb1 = xb0 + (size_t)32 * N_;

  #pragma unroll 2
  for (int mc = 0; mc < 32; ++mc) {
    int mo = mc * 32;
    short8 afrag = *reinterpret_cast<const short8*>(abase + (size_t)mo * E_);
    short8 x00 = *reinterpret_cast<const short8*>(xb0 + mo);
    short8 x01 = *reinterpret_cast<const short8*>(xb0 + mo + 16);
    short8 x10 = *reinterpret_cast<const short8*>(xb1 + mo);
    short8 x11 = *reinterpret_cast<const short8*>(xb1 + mo + 16);

    f32x16 p = __builtin_amdgcn_mfma_f32_32x32x16_bf16(afrag, bfrag, zero, 0, 0, 0);
    float q[16];
    #pragma unroll
    for (int r = 0; r < 16; ++r) q[r] = fmaxf(p[r], 0.f);

    unsigned int A0, Bb0, C0, D0, A1, Bb1, C1, D1;
    CVT_PK(A0,  q[0],  q[1]);  CVT_PK(Bb0, q[2],  q[3]);
    CVT_PK(C0,  q[4],  q[5]);  CVT_PK(D0,  q[6],  q[7]);
    CVT_PK(A1,  q[8],  q[9]);  CVT_PK(Bb1, q[10], q[11]);
    CVT_PK(C1,  q[12], q[13]); CVT_PK(D1,  q[14], q[15]);
    PL_SWAP(A0, C0);  PL_SWAP(Bb0, D0);
    PL_SWAP(A1, C1);  PL_SWAP(Bb1, D1);

    union { unsigned int u[4]; short8 s; } f0, f1;
    f0.u[0] = A0; f0.u[1] = Bb0; f0.u[2] = C0; f0.u[3] = D0;
    f1.u[0] = A1; f1.u[1] = Bb1; f1.u[2] = C1; f1.u[3] = D1;

    acc0 = __builtin_amdgcn_mfma_f32_32x32x16_bf16(x00, f0.s, acc0, 0, 0, 0);
    acc0 = __builtin_amdgcn_mfma_f32_32x32x16_bf16(x01, f1.s, acc0, 0, 0, 0);
    acc1 = __builtin_amdgcn_mfma_f32_32x32x16_bf16(x10, f0.s, acc1, 0, 0, 0);
    acc1 = __builtin_amdgcn_mfma_f32_32x32x16_bf16(x11, f1.s, acc1, 0, 0, 0);
  }

  float* yb = yT + ((size_t)part * B_ + b) * C_ * N_;
  #pragma unroll
  for (int r = 0; r < 16; ++r) {
    int cl = (r & 3) + 8 * (r >> 2) + 4 * hi;       // verified C/D row mapping
    yb[(size_t)cl * N_ + N0 + lo]        = acc0[r];
    yb[(size_t)(cl + 32) * N_ + N0 + lo] = acc1[r];
  }
}

// ---------------------------------------------------------------------------
// P4: xg2 (bf16, row-major) into xgall[:, 64:128] via LDS transpose.
// Reads yT coalesced in n; writes xgall rows coalesced. grid (32,16) x 256.
// ---------------------------------------------------------------------------
__global__ __launch_bounds__(256) void p4_xg2(
    const float* __restrict__ yT, const float* __restrict__ rsp,
    unsigned short* __restrict__ xgall)
{
  __shared__ unsigned short tile[64][72];   // 72: rows 144B (16B-aligned)
  int tid = threadIdx.x;
  int nl = tid & 63, cg = tid >> 6;         // cg 0..3, 16 c each
  int n0 = blockIdx.x * 64, b = blockIdx.y;
  int n = n0 + nl;
  float rs = rsp[(size_t)b * N_ + n] + rsp[(size_t)(B_*N_) + (size_t)b * N_ + n];
  float dn = rsqrtf(rs);
  const float* y0 = yT + (size_t)b * C_ * N_;
  const size_t PST = (size_t)B_ * C_ * N_;  // part stride
  #pragma unroll
  for (int cc = 0; cc < 16; cc += 2) {
    int c = cg * 16 + cc;
    float v0 = y0[(size_t)c * N_ + n]     + y0[PST + (size_t)c * N_ + n];
    float v1 = y0[(size_t)(c+1) * N_ + n] + y0[PST + (size_t)(c+1) * N_ + n];
    unsigned int pk = (unsigned int)f2bf(dn * v0) | ((unsigned int)f2bf(dn * v1) << 16);
    *reinterpret_cast<unsigned int*>(&tile[nl][c]) = pk;
  }
  __syncthreads();
  int q = tid & 3, j = tid >> 2;            // row j 0..63, quarter q
  uint4 va = *reinterpret_cast<const uint4*>(&tile[j][q*16]);
  uint4 vb = *reinterpret_cast<const uint4*>(&tile[j][q*16 + 8]);
  unsigned short* o = xgall + ((size_t)b * N_ + n0 + j) * 128 + 64 + q * 16;
  *reinterpret_cast<uint4*>(o)     = va;
  *reinterpret_cast<uint4*>(o + 8) = vb;
}

// ---------------------------------------------------------------------------
// K5: out[bn,o] = sum_d emb1[n,d] * (sum_ki xg[bn,ki] wp[d,ki,o]) + bias
// via bf16 MFMA. Wave = (32-row M-tile, 32-col o-half). A = xgall rows (raw),
// B = wpB frags; per-d t-chain (dual accs), f32 scale by emb1; bias = one
// extra MFMA chunk (A=emb1b, B=bp frags). grid 512 x 256 (2048 waves).
// ---------------------------------------------------------------------------
__global__ __launch_bounds__(256) void k5_out(
    const unsigned short* __restrict__ xgall, const unsigned short* __restrict__ emb1b,
    const float* __restrict__ emb1, const unsigned short* __restrict__ wpB,
    float* __restrict__ out)
{
  int tid = threadIdx.x, lane = tid & 63, wid = tid >> 6;
  int lo = lane & 31, hi = lane >> 5;
  int gw = blockIdx.x * 4 + wid;          // 0..2047
  int mt = gw >> 1;                       // M-tile 0..1023
  int o0 = (gw & 1) * 32;
  int M0 = mt * 32;                       // bn base (single b per tile)
  int n0 = M0 & (N_ - 1);

  // A-frags: 8 chunks of the xg row + bias frag (emb1b row)
  const unsigned short* arow = xgall + (size_t)(M0 + lo) * 128 + 8 * hi;
  short8 a[8];
  #pragma unroll
  for (int c8 = 0; c8 < 8; ++c8)
    a[c8] = *reinterpret_cast<const short8*>(arow + c8 * 16);
  short8 abias = *reinterpret_cast<const short8*>(
      emb1b + (size_t)(n0 + lo) * E_ + 8 * hi);

  f32x16 acc = {};
  f32x16 kzero = {};

  // emb1 row addresses for the 16 C/D rows (per-reg, half-uniform)
  int nr[16];
  #pragma unroll
  for (int r = 0; r < 16; ++r) nr[r] = n0 + (r & 3) + 8 * (r >> 2) + 4 * hi;

  #pragma unroll 2
  for (int dg = 0; dg < 8; ++dg) {        // pairs of d
    float2 e2[16];
    #pragma unroll
    for (int r = 0; r < 16; ++r)
      e2[r] = *reinterpret_cast<const float2*>(emb1 + (size_t)nr[r] * E_ + dg * 2);
    #pragma unroll
    for (int dd = 0; dd < 2; ++dd) {
      int d = dg * 2 + dd;
      const unsigned short* bbase = wpB + ((size_t)((d * 8) * 2 + hi) * 64 + o0 + lo) * 8;
      f32x16 t0 = kzero, t1 = kzero;
      #pragma unroll
      for (int c8 = 0; c8 < 8; c8 += 2) {
        short8 B0 = *reinterpret_cast<const short8*>(bbase + (size_t)(c8    ) * 1024);
        short8 B1 = *reinterpret_cast<const short8*>(bbase + (size_t)(c8 + 1) * 1024);
        t0 = __builtin_amdgcn_mfma_f32_32x32x16_bf16(a[c8],     B0, t0, 0, 0, 0);
        t1 = __builtin_amdgcn_mfma_f32_32x32x16_bf16(a[c8 + 1], B1, t1, 0, 0, 0);
      }
      #pragma unroll
      for (int r = 0; r < 16; ++r) {
        float e = dd ? e2[r].y : e2[r].x;
        acc[r] = fmaf(e, t0[r] + t1[r], acc[r]);
      }
    }
  }
  // bias: one MFMA chunk (kc = 128)
  {
    const unsigned short* bbase = wpB + ((size_t)(256 + hi) * 64 + o0 + lo) * 8;
    short8 Bb = *reinterpret_cast<const short8*>(bbase);
    acc = __builtin_amdgcn_mfma_f32_32x32x16_bf16(abias, Bb, acc, 0, 0, 0);
  }
  // store: rows per reg (verified C/D map), cols = o0+lo
  #pragma unroll
  for (int r = 0; r < 16; ++r) {
    int cl = (r & 3) + 8 * (r >> 2) + 4 * hi;
    out[(size_t)(M0 + cl) * O_ + o0 + lo] = acc[r];
  }
}

// ---------------------------------------------------------------------------
extern "C" void kernel_launch(void* const* d_in, const int* in_sizes, int n_in,
                              void* d_out, int out_size, void* d_ws, size_t ws_size,
                              hipStream_t stream)
{
  const float* x    = (const float*)d_in[0];
  const float* emb0 = (const float*)d_in[1];
  const float* emb1 = (const float*)d_in[2];
  const float* w1   = (const float*)d_in[3];
  const float* b1   = (const float*)d_in[4];
  const float* w2   = (const float*)d_in[5];
  const float* b2   = (const float*)d_in[6];
  const float* w3   = (const float*)d_in[7];
  const float* b3   = (const float*)d_in[8];
  const float* wp   = (const float*)d_in[9];
  const float* bp   = (const float*)d_in[10];
  float* out = (float*)d_out;
  float* ws  = (float*)d_ws;   // needs ~31.0 MB

  unsigned short* nvb   = (unsigned short*)(ws + NVB_OFF);
  float*          rsp   = ws + RSP_OFF;
  unsigned short* xsT   = (unsigned short*)(ws + XST_OFF);
  float*          yT    = ws + YT_OFF;
  unsigned short* xgall = (unsigned short*)(ws + XGALL_OFF);
  unsigned short* wpB   = (unsigned short*)(ws + WPB_OFF);
  unsigned short* emb1b = (unsigned short*)(ws + E1B_OFF);

  k0_prep  <<<644, 256, 0, stream>>>(wp, bp, emb1, wpB, emb1b);
  k1_hyper <<<128, 256, 0, stream>>>(x, emb0, w1, b1, w2, b2, w3, b3, nvb, xgall);
  p1_rowsum<<<512, 256, 0, stream>>>(nvb, rsp);
  p2_scaleT<<<dim3(16,16), 256, 0, stream>>>(x, rsp, xsT);
  p3_spmm  <<<512, 256, 0, stream>>>(nvb, xsT, yT);
  p4_xg2   <<<dim3(32,16), 256, 0, stream>>>(yT, rsp, xgall);
  k5_out   <<<512, 256, 0, stream>>>(xgall, emb1b, emb1, wpB, out);
}

// Round 10
// 178.470 us; speedup vs baseline: 1.4007x; 1.0413x over previous
//
#include <hip/hip_runtime.h>
#include <hip/hip_bf16.h>

// Problem constants (fixed by setup_inputs)
#define B_ 16
#define N_ 2048
#define C_ 64
#define E_ 16
#define O_ 64
#define H_ 16

typedef __attribute__((ext_vector_type(8)))  short short8;   // 8 bf16 (MFMA A/B frag)
typedef __attribute__((ext_vector_type(16))) float f32x16;   // MFMA C/D frag

// Workspace layout (float offsets). Total 12,009,984 floats = 48.0 MB.
#define NVB_OFF   0u         // nodevec bf16 [B][N][E]        262144 f
#define RSP_OFF   262144u    // rowsum  f32  [4][B][N]        131072 f
#define XST_OFF   393216u    // xs^T bf16 [B][N/32][C][32]    1048576 f
#define YT_OFF    1441792u   // A@xs f32  [4][B][C][N]        8388608 f
#define XGALL_OFF 9830400u   // xg bf16 [B][N][128] (x|xg2)   2097152 f
#define WPB_OFF   11927552u  // wpB bf16 frag-ordered         66048 f
#define E1B_OFF   11993600u  // emb1 bf16 [N][16]             16384 f

__device__ __forceinline__ unsigned short f2bf(float f) {
  union { float f; unsigned int u; } v; v.f = f;
  unsigned int r = v.u + 0x7FFFu + ((v.u >> 16) & 1u);   // RNE
  return (unsigned short)(r >> 16);
}

#define CVT_PK(dst, lo_, hi_) \
  asm("v_cvt_pk_bf16_f32 %0, %1, %2" : "=v"(dst) : "v"(lo_), "v"(hi_))
#define PL_SWAP(x_, y_) \
  asm("v_permlane32_swap_b32 %0, %1" : "+v"(x_), "+v"(y_))

// ---------------------------------------------------------------------------
// K0: prep wpB (fragment-ordered bf16 of weights_pool + bias chunk) and
// emb1 bf16. grid 644 x 256.
// ---------------------------------------------------------------------------
__global__ __launch_bounds__(256) void k0_prep(
    const float* __restrict__ wp, const float* __restrict__ bp,
    const float* __restrict__ emb1,
    unsigned short* __restrict__ wpB, unsigned short* __restrict__ emb1b)
{
  int id = blockIdx.x * 256 + threadIdx.x;
  if (id < 132096) {
    int t = id & 7, o = (id >> 3) & 63, rest = id >> 9;
    int sub = rest & 1, kc = rest >> 1;
    int q2 = sub * 8 + t;
    float v = (kc < 128) ? wp[(size_t)(kc * 16 + q2) * 64 + o]
                         : bp[(size_t)q2 * 64 + o];
    wpB[id] = f2bf(v);
  } else {
    int id2 = id - 132096;   // < 32768
    emb1b[id2] = f2bf(emb1[id2]);
  }
}

// ---------------------------------------------------------------------------
// K1: hypernet MLP + nodevec -> bf16; x-row -> bf16 xgall[:,0:64]. 128 x 256.
// ---------------------------------------------------------------------------
__global__ __launch_bounds__(256) void k1_hyper(
    const float* __restrict__ x, const float* __restrict__ emb0,
    const float* __restrict__ w1, const float* __restrict__ b1,
    const float* __restrict__ w2, const float* __restrict__ b2,
    const float* __restrict__ w3, const float* __restrict__ b3,
    unsigned short* __restrict__ nvb, unsigned short* __restrict__ xgall)
{
  __shared__ float w1s[C_*H_];
  __shared__ float b1s[H_], w2s[H_*2], b2s[2], w3s[2*E_], b3s[E_];
  int tid = threadIdx.x;
  for (int i = tid; i < C_*H_; i += 256) w1s[i] = w1[i];
  if (tid < H_)   b1s[tid] = b1[tid];
  if (tid < H_*2) w2s[tid] = w2[tid];
  if (tid < 2)    b2s[tid] = b2[tid];
  if (tid < 2*E_) w3s[tid] = w3[tid];
  if (tid < E_)   b3s[tid] = b3[tid];
  __syncthreads();

  int idx = blockIdx.x * 256 + tid;  // b*N + n
  float xr[C_];
  const float4* xp = reinterpret_cast<const float4*>(x + (size_t)idx * C_);
  #pragma unroll
  for (int j = 0; j < 16; ++j) {
    float4 v = xp[j];
    xr[4*j] = v.x; xr[4*j+1] = v.y; xr[4*j+2] = v.z; xr[4*j+3] = v.w;
  }
  // x row -> bf16 into xgall[idx][0:64]  (64 shorts = 8 x uint4)
  unsigned short xus[C_];
  #pragma unroll
  for (int c = 0; c < C_; ++c) xus[c] = f2bf(xr[c]);
  unsigned short* xo = xgall + (size_t)idx * 128;
  #pragma unroll
  for (int j = 0; j < 8; ++j)
    reinterpret_cast<uint4*>(xo)[j] = reinterpret_cast<uint4*>(xus)[j];

  float h1[H_];
  #pragma unroll
  for (int h = 0; h < H_; ++h) h1[h] = b1s[h];
  #pragma unroll 8
  for (int c = 0; c < C_; ++c) {
    float xv = xr[c];
    #pragma unroll
    for (int j = 0; j < 4; ++j) {
      float4 w = reinterpret_cast<const float4*>(&w1s[c*H_])[j];
      h1[4*j]   = fmaf(xv, w.x, h1[4*j]);
      h1[4*j+1] = fmaf(xv, w.y, h1[4*j+1]);
      h1[4*j+2] = fmaf(xv, w.z, h1[4*j+2]);
      h1[4*j+3] = fmaf(xv, w.w, h1[4*j+3]);
    }
  }
  #pragma unroll
  for (int h = 0; h < H_; ++h) h1[h] = 1.f / (1.f + __expf(-h1[h]));
  float a0 = b2s[0], a1 = b2s[1];
  #pragma unroll
  for (int h = 0; h < H_; ++h) {
    a0 = fmaf(h1[h], w2s[h*2],   a0);
    a1 = fmaf(h1[h], w2s[h*2+1], a1);
  }
  a0 = 1.f / (1.f + __expf(-a0));
  a1 = 1.f / (1.f + __expf(-a1));

  const float4* ep = reinterpret_cast<const float4*>(emb0 + (size_t)idx * E_);
  unsigned short us[E_];
  #pragma unroll
  for (int j = 0; j < 4; ++j) {
    float4 e = ep[j];
    int c = 4*j;
    us[c]   = f2bf(tanhf(e.x * (b3s[c]   + a0*w3s[c]   + a1*w3s[E_+c])));
    us[c+1] = f2bf(tanhf(e.y * (b3s[c+1] + a0*w3s[c+1] + a1*w3s[E_+c+1])));
    us[c+2] = f2bf(tanhf(e.z * (b3s[c+2] + a0*w3s[c+2] + a1*w3s[E_+c+2])));
    us[c+3] = f2bf(tanhf(e.w * (b3s[c+3] + a0*w3s[c+3] + a1*w3s[E_+c+3])));
  }
  *reinterpret_cast<short8*>(nvb + (size_t)idx * E_)     = *reinterpret_cast<short8*>(&us[0]);
  *reinterpret_cast<short8*>(nvb + (size_t)idx * E_ + 8) = *reinterpret_cast<short8*>(&us[8]);
}

// ---------------------------------------------------------------------------
// P1: rowsum partials via MFMA (swapped QK^T, lane owns n).
// grid 1024 (xcd-swizzled) x 256: 16 rb x 16 b x 4 part; m-quarter = 512.
// ---------------------------------------------------------------------------
__global__ __launch_bounds__(256, 4) void p1_rowsum(
    const unsigned short* __restrict__ nvb, float* __restrict__ rsp)
{
  int tid = threadIdx.x, lane = tid & 63, wid = tid >> 6;
  int lo = lane & 31, hi = lane >> 5;
  int orig = blockIdx.x;
  int eff = (orig & 7) * 128 + (orig >> 3);      // bijective XCD swizzle (1024 = 8*128)
  int rb = eff & 15, b = (eff >> 4) & 15, part = eff >> 8;   // part 0..3
  int N0 = rb * 128 + wid * 32;

  short8 bfrag = *reinterpret_cast<const short8*>(
      nvb + ((size_t)b * N_ + N0 + lo) * E_ + 8 * hi);
  f32x16 zero = {};
  float rs = 0.f;
  const unsigned short* abase =
      nvb + ((size_t)b * N_ + part * 512 + lo) * E_ + 8 * hi;
  #pragma unroll 2
  for (int mc = 0; mc < 16; ++mc) {
    short8 afrag = *reinterpret_cast<const short8*>(abase + (size_t)mc * 32 * E_);
    f32x16 p = __builtin_amdgcn_mfma_f32_32x32x16_bf16(afrag, bfrag, zero, 0, 0, 0);
    #pragma unroll
    for (int r = 0; r < 16; ++r) rs += fmaxf(p[r], 0.f);
  }
  rs += __shfl_xor(rs, 32, 64);
  if (lane < 32) rsp[((size_t)part * B_ + b) * N_ + N0 + lo] = rs;
}

// ---------------------------------------------------------------------------
// P2: xs^T tiled: xsT[b][m>>5][c][m&31] = bf16( d_m * x[b][m][c] ).
// grid (16,16) x 256; thread = (c, g); 32 m each -> one 64B-contig tile row.
// ---------------------------------------------------------------------------
__global__ __launch_bounds__(256) void p2_scaleT(
    const float* __restrict__ x, const float* __restrict__ rsp,
    unsigned short* __restrict__ xsT)
{
  int tid = threadIdx.x;
  int c = tid & 63, g = tid >> 6;
  int m0 = blockIdx.x * 128 + g * 32;            // 32-aligned
  int b  = blockIdx.y;
  const float* rp = rsp + (size_t)b * N_;
  const size_t RST = (size_t)B_ * N_;            // part stride in rsp
  unsigned int pk[16];
  #pragma unroll
  for (int k = 0; k < 32; ++k) {
    int m = m0 + k;
    float s = rp[m] + rp[RST + m] + rp[2*RST + m] + rp[3*RST + m];
    float d = rsqrtf(s);
    float v = d * x[((size_t)b * N_ + m) * C_ + c];
    unsigned short us = f2bf(v);
    if (k & 1) pk[k >> 1] |= ((unsigned int)us) << 16;
    else       pk[k >> 1]  = us;
  }
  // tile-row: ((b*64 + m0/32)*64 + c)*32, 64B contiguous
  unsigned short* o = xsT + (((size_t)b * 64 + (m0 >> 5)) * 64 + c) * 32;
  #pragma unroll
  for (int j = 0; j < 4; ++j)
    reinterpret_cast<uint4*>(o)[j] = *reinterpret_cast<uint4*>(&pk[4*j]);
}

// ---------------------------------------------------------------------------
// P3: y^T[part][b][c][n] = sum_{m in quarter} relu(nv_n . nv_m) * xs[m][c].
// grid 1024 x 256: 16 rb x 16 b x 4 part. xsT tiled -> PV A-loads hit a
// contiguous 2KB block per chunk. 5 MFMA / 32-m chunk, 16 chunks.
// ---------------------------------------------------------------------------
__global__ __launch_bounds__(256, 4) void p3_spmm(
    const unsigned short* __restrict__ nvb, const unsigned short* __restrict__ xsT,
    float* __restrict__ yT)
{
  int tid = threadIdx.x, lane = tid & 63, wid = tid >> 6;
  int lo = lane & 31, hi = lane >> 5;
  int orig = blockIdx.x;
  int eff = (orig & 7) * 128 + (orig >> 3);
  int rb = eff & 15, b = (eff >> 4) & 15, part = eff >> 8;   // part 0..3
  int N0 = rb * 128 + wid * 32;

  short8 bfrag = *reinterpret_cast<const short8*>(
      nvb + ((size_t)b * N_ + N0 + lo) * E_ + 8 * hi);
  f32x16 acc0 = {}, acc1 = {};
  f32x16 zero = {};
  const unsigned short* abase =
      nvb + ((size_t)b * N_ + part * 512 + lo) * E_ + 8 * hi;
  // tile base: [b][part*16 + mc][c][ms]; lane offset lo*32 + 8*hi
  const unsigned short* xtile =
      xsT + (((size_t)b * 64 + part * 16) * 64) * 32 + lo * 32 + 8 * hi;

  #pragma unroll 2
  for (int mc = 0; mc < 16; ++mc) {
    short8 afrag = *reinterpret_cast<const short8*>(abase + (size_t)mc * 32 * E_);
    const unsigned short* xt = xtile + (size_t)mc * 2048;   // 64c * 32ms
    short8 x00 = *reinterpret_cast<const short8*>(xt);            // c=lo,    ms=8hi+t
    short8 x01 = *reinterpret_cast<const short8*>(xt + 16);       // c=lo,    ms=16+8hi+t
    short8 x10 = *reinterpret_cast<const short8*>(xt + 1024);     // c=lo+32, ms=8hi+t
    short8 x11 = *reinterpret_cast<const short8*>(xt + 1024 + 16);

    f32x16 p = __builtin_amdgcn_mfma_f32_32x32x16_bf16(afrag, bfrag, zero, 0, 0, 0);
    float q[16];
    #pragma unroll
    for (int r = 0; r < 16; ++r) q[r] = fmaxf(p[r], 0.f);

    unsigned int A0, Bb0, C0, D0, A1, Bb1, C1, D1;
    CVT_PK(A0,  q[0],  q[1]);  CVT_PK(Bb0, q[2],  q[3]);
    CVT_PK(C0,  q[4],  q[5]);  CVT_PK(D0,  q[6],  q[7]);
    CVT_PK(A1,  q[8],  q[9]);  CVT_PK(Bb1, q[10], q[11]);
    CVT_PK(C1,  q[12], q[13]); CVT_PK(D1,  q[14], q[15]);
    PL_SWAP(A0, C0);  PL_SWAP(Bb0, D0);
    PL_SWAP(A1, C1);  PL_SWAP(Bb1, D1);

    union { unsigned int u[4]; short8 s; } f0, f1;
    f0.u[0] = A0; f0.u[1] = Bb0; f0.u[2] = C0; f0.u[3] = D0;
    f1.u[0] = A1; f1.u[1] = Bb1; f1.u[2] = C1; f1.u[3] = D1;

    acc0 = __builtin_amdgcn_mfma_f32_32x32x16_bf16(x00, f0.s, acc0, 0, 0, 0);
    acc0 = __builtin_amdgcn_mfma_f32_32x32x16_bf16(x01, f1.s, acc0, 0, 0, 0);
    acc1 = __builtin_amdgcn_mfma_f32_32x32x16_bf16(x10, f0.s, acc1, 0, 0, 0);
    acc1 = __builtin_amdgcn_mfma_f32_32x32x16_bf16(x11, f1.s, acc1, 0, 0, 0);
  }

  float* yb = yT + ((size_t)part * B_ + b) * C_ * N_;
  #pragma unroll
  for (int r = 0; r < 16; ++r) {
    int cl = (r & 3) + 8 * (r >> 2) + 4 * hi;       // verified C/D row mapping
    yb[(size_t)cl * N_ + N0 + lo]        = acc0[r];
    yb[(size_t)(cl + 32) * N_ + N0 + lo] = acc1[r];
  }
}

// ---------------------------------------------------------------------------
// P4: xg2 (bf16, row-major) into xgall[:, 64:128] via LDS transpose.
// Sums 4 yT parts. grid (32,16) x 256.
// ---------------------------------------------------------------------------
__global__ __launch_bounds__(256) void p4_xg2(
    const float* __restrict__ yT, const float* __restrict__ rsp,
    unsigned short* __restrict__ xgall)
{
  __shared__ unsigned short tile[64][72];   // 72: rows 144B (16B-aligned)
  int tid = threadIdx.x;
  int nl = tid & 63, cg = tid >> 6;         // cg 0..3, 16 c each
  int n0 = blockIdx.x * 64, b = blockIdx.y;
  int n = n0 + nl;
  const size_t RST = (size_t)B_ * N_;
  float rs = rsp[(size_t)b * N_ + n]       + rsp[RST + (size_t)b * N_ + n]
           + rsp[2*RST + (size_t)b * N_ + n] + rsp[3*RST + (size_t)b * N_ + n];
  float dn = rsqrtf(rs);
  const float* y0 = yT + (size_t)b * C_ * N_;
  const size_t PST = (size_t)B_ * C_ * N_;  // part stride
  #pragma unroll
  for (int cc = 0; cc < 16; cc += 2) {
    int c = cg * 16 + cc;
    size_t o0 = (size_t)c * N_ + n, o1 = (size_t)(c+1) * N_ + n;
    float v0 = y0[o0] + y0[PST + o0] + y0[2*PST + o0] + y0[3*PST + o0];
    float v1 = y0[o1] + y0[PST + o1] + y0[2*PST + o1] + y0[3*PST + o1];
    unsigned int pk = (unsigned int)f2bf(dn * v0) | ((unsigned int)f2bf(dn * v1) << 16);
    *reinterpret_cast<unsigned int*>(&tile[nl][c]) = pk;
  }
  __syncthreads();
  int q = tid & 3, j = tid >> 2;            // row j 0..63, quarter q
  uint4 va = *reinterpret_cast<const uint4*>(&tile[j][q*16]);
  uint4 vb = *reinterpret_cast<const uint4*>(&tile[j][q*16 + 8]);
  unsigned short* o = xgall + ((size_t)b * N_ + n0 + j) * 128 + 64 + q * 16;
  *reinterpret_cast<uint4*>(o)     = va;
  *reinterpret_cast<uint4*>(o + 8) = vb;
}

// ---------------------------------------------------------------------------
// K5: out[bn,o] = sum_d emb1[n,d] * (sum_ki xg[bn,ki] wp[d,ki,o]) + bias
// via bf16 MFMA. grid 512 x 256 (2048 waves).
// ---------------------------------------------------------------------------
__global__ __launch_bounds__(256) void k5_out(
    const unsigned short* __restrict__ xgall, const unsigned short* __restrict__ emb1b,
    const float* __restrict__ emb1, const unsigned short* __restrict__ wpB,
    float* __restrict__ out)
{
  int tid = threadIdx.x, lane = tid & 63, wid = tid >> 6;
  int lo = lane & 31, hi = lane >> 5;
  int gw = blockIdx.x * 4 + wid;          // 0..2047
  int mt = gw >> 1;                       // M-tile 0..1023
  int o0 = (gw & 1) * 32;
  int M0 = mt * 32;                       // bn base (single b per tile)
  int n0 = M0 & (N_ - 1);

  const unsigned short* arow = xgall + (size_t)(M0 + lo) * 128 + 8 * hi;
  short8 a[8];
  #pragma unroll
  for (int c8 = 0; c8 < 8; ++c8)
    a[c8] = *reinterpret_cast<const short8*>(arow + c8 * 16);
  short8 abias = *reinterpret_cast<const short8*>(
      emb1b + (size_t)(n0 + lo) * E_ + 8 * hi);

  f32x16 acc = {};
  f32x16 kzero = {};

  int nr[16];
  #pragma unroll
  for (int r = 0; r < 16; ++r) nr[r] = n0 + (r & 3) + 8 * (r >> 2) + 4 * hi;

  #pragma unroll 2
  for (int dg = 0; dg < 8; ++dg) {        // pairs of d
    float2 e2[16];
    #pragma unroll
    for (int r = 0; r < 16; ++r)
      e2[r] = *reinterpret_cast<const float2*>(emb1 + (size_t)nr[r] * E_ + dg * 2);
    #pragma unroll
    for (int dd = 0; dd < 2; ++dd) {
      int d = dg * 2 + dd;
      const unsigned short* bbase = wpB + ((size_t)((d * 8) * 2 + hi) * 64 + o0 + lo) * 8;
      f32x16 t0 = kzero, t1 = kzero;
      #pragma unroll
      for (int c8 = 0; c8 < 8; c8 += 2) {
        short8 B0 = *reinterpret_cast<const short8*>(bbase + (size_t)(c8    ) * 1024);
        short8 B1 = *reinterpret_cast<const short8*>(bbase + (size_t)(c8 + 1) * 1024);
        t0 = __builtin_amdgcn_mfma_f32_32x32x16_bf16(a[c8],     B0, t0, 0, 0, 0);
        t1 = __builtin_amdgcn_mfma_f32_32x32x16_bf16(a[c8 + 1], B1, t1, 0, 0, 0);
      }
      #pragma unroll
      for (int r = 0; r < 16; ++r) {
        float e = dd ? e2[r].y : e2[r].x;
        acc[r] = fmaf(e, t0[r] + t1[r], acc[r]);
      }
    }
  }
  // bias: one MFMA chunk (kc = 128)
  {
    const unsigned short* bbase = wpB + ((size_t)(256 + hi) * 64 + o0 + lo) * 8;
    short8 Bb = *reinterpret_cast<const short8*>(bbase);
    acc = __builtin_amdgcn_mfma_f32_32x32x16_bf16(abias, Bb, acc, 0, 0, 0);
  }
  #pragma unroll
  for (int r = 0; r < 16; ++r) {
    int cl = (r & 3) + 8 * (r >> 2) + 4 * hi;
    out[(size_t)(M0 + cl) * O_ + o0 + lo] = acc[r];
  }
}

// ---------------------------------------------------------------------------
extern "C" void kernel_launch(void* const* d_in, const int* in_sizes, int n_in,
                              void* d_out, int out_size, void* d_ws, size_t ws_size,
                              hipStream_t stream)
{
  const float* x    = (const float*)d_in[0];
  const float* emb0 = (const float*)d_in[1];
  const float* emb1 = (const float*)d_in[2];
  const float* w1   = (const float*)d_in[3];
  const float* b1   = (const float*)d_in[4];
  const float* w2   = (const float*)d_in[5];
  const float* b2   = (const float*)d_in[6];
  const float* w3   = (const float*)d_in[7];
  const float* b3   = (const float*)d_in[8];
  const float* wp   = (const float*)d_in[9];
  const float* bp   = (const float*)d_in[10];
  float* out = (float*)d_out;
  float* ws  = (float*)d_ws;   // needs ~48 MB

  unsigned short* nvb   = (unsigned short*)(ws + NVB_OFF);
  float*          rsp   = ws + RSP_OFF;
  unsigned short* xsT   = (unsigned short*)(ws + XST_OFF);
  float*          yT    = ws + YT_OFF;
  unsigned short* xgall = (unsigned short*)(ws + XGALL_OFF);
  unsigned short* wpB   = (unsigned short*)(ws + WPB_OFF);
  unsigned short* emb1b = (unsigned short*)(ws + E1B_OFF);

  k0_prep  <<<644, 256, 0, stream>>>(wp, bp, emb1, wpB, emb1b);
  k1_hyper <<<128, 256, 0, stream>>>(x, emb0, w1, b1, w2, b2, w3, b3, nvb, xgall);
  p1_rowsum<<<1024, 256, 0, stream>>>(nvb, rsp);
  p2_scaleT<<<dim3(16,16), 256, 0, stream>>>(x, rsp, xsT);
  p3_spmm  <<<1024, 256, 0, stream>>>(nvb, xsT, yT);
  p4_xg2   <<<dim3(32,16), 256, 0, stream>>>(yT, rsp, xgall);
  k5_out   <<<512, 256, 0, stream>>>(xgall, emb1b, emb1, wpB, out);
}

// Round 11
// 177.413 us; speedup vs baseline: 1.4091x; 1.0060x over previous
//
#include <hip/hip_runtime.h>
#include <hip/hip_bf16.h>

// Problem constants (fixed by setup_inputs)
#define B_ 16
#define N_ 2048
#define C_ 64
#define E_ 16
#define O_ 64
#define H_ 16

typedef __attribute__((ext_vector_type(8)))  short short8;   // 8 bf16 (MFMA A/B frag)
typedef __attribute__((ext_vector_type(16))) float f32x16;   // MFMA C/D frag

// Workspace layout (float offsets). Total ~7,815,680 floats = 31.3 MB.
#define NVB_OFF   0u         // nodevec bf16 [B][N][E]        262144 f
#define RSP_OFF   262144u    // rowsum  f32  [4][B][N]        131072 f
#define XST_OFF   393216u    // xs^T bf16 [B][N/32][C][32]    1048576 f
#define YT_OFF    1441792u   // A@xs bf16 [4][B][C][N]        4194304 f
#define XGALL_OFF 5636096u   // xg bf16 [B][N][128] (x|xg2)   2097152 f
#define WPB_OFF   7733248u   // wpB bf16 frag-ordered         66048 f
#define E1B_OFF   7799296u   // emb1 bf16 [N][16]             16384 f

__device__ __forceinline__ unsigned short f2bf(float f) {
  union { float f; unsigned int u; } v; v.f = f;
  unsigned int r = v.u + 0x7FFFu + ((v.u >> 16) & 1u);   // RNE
  return (unsigned short)(r >> 16);
}
__device__ __forceinline__ float bf2f(unsigned short u) {
  union { unsigned int i; float f; } v; v.i = ((unsigned int)u) << 16;
  return v.f;
}

#define CVT_PK(dst, lo_, hi_) \
  asm("v_cvt_pk_bf16_f32 %0, %1, %2" : "=v"(dst) : "v"(lo_), "v"(hi_))
#define PL_SWAP(x_, y_) \
  asm("v_permlane32_swap_b32 %0, %1" : "+v"(x_), "+v"(y_))

// ---------------------------------------------------------------------------
// K01: fused prep + hypernet. Blocks 0..127: k1 (MLP + nodevec + x->bf16),
// with LDS-staged coalesced x loads. Blocks 128..771: k0 (wpB/emb1b prep).
// ---------------------------------------------------------------------------
__global__ __launch_bounds__(256) void k01_fused(
    const float* __restrict__ x, const float* __restrict__ emb0,
    const float* __restrict__ w1, const float* __restrict__ b1,
    const float* __restrict__ w2, const float* __restrict__ b2,
    const float* __restrict__ w3, const float* __restrict__ b3,
    const float* __restrict__ wp, const float* __restrict__ bp,
    const float* __restrict__ emb1,
    unsigned short* __restrict__ nvb, unsigned short* __restrict__ xgall,
    unsigned short* __restrict__ wpB, unsigned short* __restrict__ emb1b)
{
  int tid = threadIdx.x;
  if (blockIdx.x >= 128) {
    // ---- k0 work ----
    int id = (blockIdx.x - 128) * 256 + tid;
    if (id < 132096) {
      int t = id & 7, o = (id >> 3) & 63, rest = id >> 9;
      int sub = rest & 1, kc = rest >> 1;
      int q2 = sub * 8 + t;
      float v = (kc < 128) ? wp[(size_t)(kc * 16 + q2) * 64 + o]
                           : bp[(size_t)q2 * 64 + o];
      wpB[id] = f2bf(v);
    } else {
      int id2 = id - 132096;   // < 32768
      emb1b[id2] = f2bf(emb1[id2]);
    }
    return;
  }

  // ---- k1 work ----
  __shared__ float xt[128][65];     // 33.3 KB staging, 65-pad: conflict-free
  __shared__ float w1s[C_*H_];
  __shared__ float b1s[H_], w2s[H_*2], b2s[2], w3s[2*E_], b3s[E_];
  for (int i = tid; i < C_*H_; i += 256) w1s[i] = w1[i];
  if (tid < H_)   b1s[tid] = b1[tid];
  if (tid < H_*2) w2s[tid] = w2[tid];
  if (tid < 2)    b2s[tid] = b2[tid];
  if (tid < 2*E_) w3s[tid] = w3[tid];
  if (tid < E_)   b3s[tid] = b3[tid];

  int base = blockIdx.x * 256;      // row base (b*N + n space)
  float xr[C_];
  #pragma unroll
  for (int ph = 0; ph < 2; ++ph) {
    // coalesced load of 128 rows (2048 float4, 8 per thread)
    const float4* src = reinterpret_cast<const float4*>(x + (size_t)(base + ph*128) * C_);
    #pragma unroll
    for (int j = 0; j < 8; ++j) {
      int i = j * 256 + tid;        // float4 index 0..2047
      float4 v = src[i];
      int row = i >> 4, c4 = (i & 15) * 4;
      xt[row][c4]   = v.x; xt[row][c4+1] = v.y;
      xt[row][c4+2] = v.z; xt[row][c4+3] = v.w;
    }
    __syncthreads();
    if ((tid >> 7) == ph) {
      int lr = tid & 127;
      #pragma unroll
      for (int j = 0; j < C_; ++j) xr[j] = xt[lr][j];
    }
    __syncthreads();
  }

  int idx = base + tid;  // b*N + n
  // x row -> bf16 into xgall[idx][0:64]
  unsigned short xus[C_];
  #pragma unroll
  for (int c = 0; c < C_; ++c) xus[c] = f2bf(xr[c]);
  unsigned short* xo = xgall + (size_t)idx * 128;
  #pragma unroll
  for (int j = 0; j < 8; ++j)
    reinterpret_cast<uint4*>(xo)[j] = reinterpret_cast<uint4*>(xus)[j];

  float h1[H_];
  #pragma unroll
  for (int h = 0; h < H_; ++h) h1[h] = b1s[h];
  #pragma unroll 8
  for (int c = 0; c < C_; ++c) {
    float xv = xr[c];
    #pragma unroll
    for (int j = 0; j < 4; ++j) {
      float4 w = reinterpret_cast<const float4*>(&w1s[c*H_])[j];
      h1[4*j]   = fmaf(xv, w.x, h1[4*j]);
      h1[4*j+1] = fmaf(xv, w.y, h1[4*j+1]);
      h1[4*j+2] = fmaf(xv, w.z, h1[4*j+2]);
      h1[4*j+3] = fmaf(xv, w.w, h1[4*j+3]);
    }
  }
  #pragma unroll
  for (int h = 0; h < H_; ++h) h1[h] = 1.f / (1.f + __expf(-h1[h]));
  float a0 = b2s[0], a1 = b2s[1];
  #pragma unroll
  for (int h = 0; h < H_; ++h) {
    a0 = fmaf(h1[h], w2s[h*2],   a0);
    a1 = fmaf(h1[h], w2s[h*2+1], a1);
  }
  a0 = 1.f / (1.f + __expf(-a0));
  a1 = 1.f / (1.f + __expf(-a1));

  const float4* ep = reinterpret_cast<const float4*>(emb0 + (size_t)idx * E_);
  unsigned short us[E_];
  #pragma unroll
  for (int j = 0; j < 4; ++j) {
    float4 e = ep[j];
    int c = 4*j;
    us[c]   = f2bf(tanhf(e.x * (b3s[c]   + a0*w3s[c]   + a1*w3s[E_+c])));
    us[c+1] = f2bf(tanhf(e.y * (b3s[c+1] + a0*w3s[c+1] + a1*w3s[E_+c+1])));
    us[c+2] = f2bf(tanhf(e.z * (b3s[c+2] + a0*w3s[c+2] + a1*w3s[E_+c+2])));
    us[c+3] = f2bf(tanhf(e.w * (b3s[c+3] + a0*w3s[c+3] + a1*w3s[E_+c+3])));
  }
  *reinterpret_cast<short8*>(nvb + (size_t)idx * E_)     = *reinterpret_cast<short8*>(&us[0]);
  *reinterpret_cast<short8*>(nvb + (size_t)idx * E_ + 8) = *reinterpret_cast<short8*>(&us[8]);
}

// ---------------------------------------------------------------------------
// P1: rowsum partials via MFMA (swapped QK^T, lane owns n).
// grid 1024 (xcd-swizzled) x 256: 16 rb x 16 b x 4 part; m-quarter = 512.
// ---------------------------------------------------------------------------
__global__ __launch_bounds__(256, 4) void p1_rowsum(
    const unsigned short* __restrict__ nvb, float* __restrict__ rsp)
{
  int tid = threadIdx.x, lane = tid & 63, wid = tid >> 6;
  int lo = lane & 31, hi = lane >> 5;
  int orig = blockIdx.x;
  int eff = (orig & 7) * 128 + (orig >> 3);      // bijective XCD swizzle (1024 = 8*128)
  int rb = eff & 15, b = (eff >> 4) & 15, part = eff >> 8;   // part 0..3
  int N0 = rb * 128 + wid * 32;

  short8 bfrag = *reinterpret_cast<const short8*>(
      nvb + ((size_t)b * N_ + N0 + lo) * E_ + 8 * hi);
  f32x16 zero = {};
  float rs = 0.f;
  const unsigned short* abase =
      nvb + ((size_t)b * N_ + part * 512 + lo) * E_ + 8 * hi;
  #pragma unroll 2
  for (int mc = 0; mc < 16; ++mc) {
    short8 afrag = *reinterpret_cast<const short8*>(abase + (size_t)mc * 32 * E_);
    f32x16 p = __builtin_amdgcn_mfma_f32_32x32x16_bf16(afrag, bfrag, zero, 0, 0, 0);
    #pragma unroll
    for (int r = 0; r < 16; ++r) rs += fmaxf(p[r], 0.f);
  }
  rs += __shfl_xor(rs, 32, 64);
  if (lane < 32) rsp[((size_t)part * B_ + b) * N_ + N0 + lo] = rs;
}

// ---------------------------------------------------------------------------
// P2: xs^T tiled: xsT[b][m>>5][c][m&31] = bf16( d_m * x[b][m][c] ).
// grid (16,16) x 256; thread = (c, g); 32 m each -> 64B-contig tile row.
// ---------------------------------------------------------------------------
__global__ __launch_bounds__(256) void p2_scaleT(
    const float* __restrict__ x, const float* __restrict__ rsp,
    unsigned short* __restrict__ xsT)
{
  int tid = threadIdx.x;
  int c = tid & 63, g = tid >> 6;
  int m0 = blockIdx.x * 128 + g * 32;            // 32-aligned
  int b  = blockIdx.y;
  const float* rp = rsp + (size_t)b * N_;
  const size_t RST = (size_t)B_ * N_;            // part stride in rsp
  unsigned int pk[16];
  #pragma unroll
  for (int k = 0; k < 32; ++k) {
    int m = m0 + k;
    float s = rp[m] + rp[RST + m] + rp[2*RST + m] + rp[3*RST + m];
    float d = rsqrtf(s);
    float v = d * x[((size_t)b * N_ + m) * C_ + c];
    unsigned short us = f2bf(v);
    if (k & 1) pk[k >> 1] |= ((unsigned int)us) << 16;
    else       pk[k >> 1]  = us;
  }
  unsigned short* o = xsT + (((size_t)b * 64 + (m0 >> 5)) * 64 + c) * 32;
  #pragma unroll
  for (int j = 0; j < 4; ++j)
    reinterpret_cast<uint4*>(o)[j] = *reinterpret_cast<uint4*>(&pk[4*j]);
}

// ---------------------------------------------------------------------------
// P3: y^T[part][b][c][n] = sum_{m in quarter} relu(nv_n . nv_m) * xs[m][c].
// grid 1024 x 256. yT stored bf16 (halves traffic vs f32).
// ---------------------------------------------------------------------------
__global__ __launch_bounds__(256, 4) void p3_spmm(
    const unsigned short* __restrict__ nvb, const unsigned short* __restrict__ xsT,
    unsigned short* __restrict__ yT)
{
  int tid = threadIdx.x, lane = tid & 63, wid = tid >> 6;
  int lo = lane & 31, hi = lane >> 5;
  int orig = blockIdx.x;
  int eff = (orig & 7) * 128 + (orig >> 3);
  int rb = eff & 15, b = (eff >> 4) & 15, part = eff >> 8;   // part 0..3
  int N0 = rb * 128 + wid * 32;

  short8 bfrag = *reinterpret_cast<const short8*>(
      nvb + ((size_t)b * N_ + N0 + lo) * E_ + 8 * hi);
  f32x16 acc0 = {}, acc1 = {};
  f32x16 zero = {};
  const unsigned short* abase =
      nvb + ((size_t)b * N_ + part * 512 + lo) * E_ + 8 * hi;
  const unsigned short* xtile =
      xsT + (((size_t)b * 64 + part * 16) * 64) * 32 + lo * 32 + 8 * hi;

  #pragma unroll 2
  for (int mc = 0; mc < 16; ++mc) {
    short8 afrag = *reinterpret_cast<const short8*>(abase + (size_t)mc * 32 * E_);
    const unsigned short* xt = xtile + (size_t)mc * 2048;   // 64c * 32ms
    short8 x00 = *reinterpret_cast<const short8*>(xt);
    short8 x01 = *reinterpret_cast<const short8*>(xt + 16);
    short8 x10 = *reinterpret_cast<const short8*>(xt + 1024);
    short8 x11 = *reinterpret_cast<const short8*>(xt + 1024 + 16);

    f32x16 p = __builtin_amdgcn_mfma_f32_32x32x16_bf16(afrag, bfrag, zero, 0, 0, 0);
    float q[16];
    #pragma unroll
    for (int r = 0; r < 16; ++r) q[r] = fmaxf(p[r], 0.f);

    unsigned int A0, Bb0, C0, D0, A1, Bb1, C1, D1;
    CVT_PK(A0,  q[0],  q[1]);  CVT_PK(Bb0, q[2],  q[3]);
    CVT_PK(C0,  q[4],  q[5]);  CVT_PK(D0,  q[6],  q[7]);
    CVT_PK(A1,  q[8],  q[9]);  CVT_PK(Bb1, q[10], q[11]);
    CVT_PK(C1,  q[12], q[13]); CVT_PK(D1,  q[14], q[15]);
    PL_SWAP(A0, C0);  PL_SWAP(Bb0, D0);
    PL_SWAP(A1, C1);  PL_SWAP(Bb1, D1);

    union { unsigned int u[4]; short8 s; } f0, f1;
    f0.u[0] = A0; f0.u[1] = Bb0; f0.u[2] = C0; f0.u[3] = D0;
    f1.u[0] = A1; f1.u[1] = Bb1; f1.u[2] = C1; f1.u[3] = D1;

    acc0 = __builtin_amdgcn_mfma_f32_32x32x16_bf16(x00, f0.s, acc0, 0, 0, 0);
    acc0 = __builtin_amdgcn_mfma_f32_32x32x16_bf16(x01, f1.s, acc0, 0, 0, 0);
    acc1 = __builtin_amdgcn_mfma_f32_32x32x16_bf16(x10, f0.s, acc1, 0, 0, 0);
    acc1 = __builtin_amdgcn_mfma_f32_32x32x16_bf16(x11, f1.s, acc1, 0, 0, 0);
  }

  unsigned short* yb = yT + ((size_t)part * B_ + b) * C_ * N_;
  #pragma unroll
  for (int r = 0; r < 16; ++r) {
    int cl = (r & 3) + 8 * (r >> 2) + 4 * hi;       // verified C/D row mapping
    yb[(size_t)cl * N_ + N0 + lo]        = f2bf(acc0[r]);
    yb[(size_t)(cl + 32) * N_ + N0 + lo] = f2bf(acc1[r]);
  }
}

// ---------------------------------------------------------------------------
// P4: xg2 (bf16, row-major) into xgall[:, 64:128] via LDS transpose.
// Sums 4 bf16 yT parts. grid (32,16) x 256.
// ---------------------------------------------------------------------------
__global__ __launch_bounds__(256) void p4_xg2(
    const unsigned short* __restrict__ yT, const float* __restrict__ rsp,
    unsigned short* __restrict__ xgall)
{
  __shared__ unsigned short tile[64][72];   // 72: rows 144B (16B-aligned)
  int tid = threadIdx.x;
  int nl = tid & 63, cg = tid >> 6;         // cg 0..3, 16 c each
  int n0 = blockIdx.x * 64, b = blockIdx.y;
  int n = n0 + nl;
  const size_t RST = (size_t)B_ * N_;
  float rs = rsp[(size_t)b * N_ + n]         + rsp[RST + (size_t)b * N_ + n]
           + rsp[2*RST + (size_t)b * N_ + n] + rsp[3*RST + (size_t)b * N_ + n];
  float dn = rsqrtf(rs);
  const unsigned short* y0 = yT + (size_t)b * C_ * N_;
  const size_t PST = (size_t)B_ * C_ * N_;  // part stride (ushorts)
  #pragma unroll
  for (int cc = 0; cc < 16; cc += 2) {
    int c = cg * 16 + cc;
    size_t o0 = (size_t)c * N_ + n, o1 = (size_t)(c+1) * N_ + n;
    float v0 = bf2f(y0[o0]) + bf2f(y0[PST + o0]) + bf2f(y0[2*PST + o0]) + bf2f(y0[3*PST + o0]);
    float v1 = bf2f(y0[o1]) + bf2f(y0[PST + o1]) + bf2f(y0[2*PST + o1]) + bf2f(y0[3*PST + o1]);
    unsigned int pk = (unsigned int)f2bf(dn * v0) | ((unsigned int)f2bf(dn * v1) << 16);
    *reinterpret_cast<unsigned int*>(&tile[nl][c]) = pk;
  }
  __syncthreads();
  int q = tid & 3, j = tid >> 2;            // row j 0..63, quarter q
  uint4 va = *reinterpret_cast<const uint4*>(&tile[j][q*16]);
  uint4 vb = *reinterpret_cast<const uint4*>(&tile[j][q*16 + 8]);
  unsigned short* o = xgall + ((size_t)b * N_ + n0 + j) * 128 + 64 + q * 16;
  *reinterpret_cast<uint4*>(o)     = va;
  *reinterpret_cast<uint4*>(o + 8) = vb;
}

// ---------------------------------------------------------------------------
// K5: out[bn,o] = sum_d emb1[n,d] * (sum_ki xg[bn,ki] wp[d,ki,o]) + bias
// via bf16 MFMA. grid 512 x 256 (2048 waves).
// ---------------------------------------------------------------------------
__global__ __launch_bounds__(256) void k5_out(
    const unsigned short* __restrict__ xgall, const unsigned short* __restrict__ emb1b,
    const float* __restrict__ emb1, const unsigned short* __restrict__ wpB,
    float* __restrict__ out)
{
  int tid = threadIdx.x, lane = tid & 63, wid = tid >> 6;
  int lo = lane & 31, hi = lane >> 5;
  int gw = blockIdx.x * 4 + wid;          // 0..2047
  int mt = gw >> 1;                       // M-tile 0..1023
  int o0 = (gw & 1) * 32;
  int M0 = mt * 32;                       // bn base (single b per tile)
  int n0 = M0 & (N_ - 1);

  const unsigned short* arow = xgall + (size_t)(M0 + lo) * 128 + 8 * hi;
  short8 a[8];
  #pragma unroll
  for (int c8 = 0; c8 < 8; ++c8)
    a[c8] = *reinterpret_cast<const short8*>(arow + c8 * 16);
  short8 abias = *reinterpret_cast<const short8*>(
      emb1b + (size_t)(n0 + lo) * E_ + 8 * hi);

  f32x16 acc = {};
  f32x16 kzero = {};

  int nr[16];
  #pragma unroll
  for (int r = 0; r < 16; ++r) nr[r] = n0 + (r & 3) + 8 * (r >> 2) + 4 * hi;

  #pragma unroll 2
  for (int dg = 0; dg < 8; ++dg) {        // pairs of d
    float2 e2[16];
    #pragma unroll
    for (int r = 0; r < 16; ++r)
      e2[r] = *reinterpret_cast<const float2*>(emb1 + (size_t)nr[r] * E_ + dg * 2);
    #pragma unroll
    for (int dd = 0; dd < 2; ++dd) {
      int d = dg * 2 + dd;
      const unsigned short* bbase = wpB + ((size_t)((d * 8) * 2 + hi) * 64 + o0 + lo) * 8;
      f32x16 t0 = kzero, t1 = kzero;
      #pragma unroll
      for (int c8 = 0; c8 < 8; c8 += 2) {
        short8 B0 = *reinterpret_cast<const short8*>(bbase + (size_t)(c8    ) * 1024);
        short8 B1 = *reinterpret_cast<const short8*>(bbase + (size_t)(c8 + 1) * 1024);
        t0 = __builtin_amdgcn_mfma_f32_32x32x16_bf16(a[c8],     B0, t0, 0, 0, 0);
        t1 = __builtin_amdgcn_mfma_f32_32x32x16_bf16(a[c8 + 1], B1, t1, 0, 0, 0);
      }
      #pragma unroll
      for (int r = 0; r < 16; ++r) {
        float e = dd ? e2[r].y : e2[r].x;
        acc[r] = fmaf(e, t0[r] + t1[r], acc[r]);
      }
    }
  }
  // bias: one MFMA chunk (kc = 128)
  {
    const unsigned short* bbase = wpB + ((size_t)(256 + hi) * 64 + o0 + lo) * 8;
    short8 Bb = *reinterpret_cast<const short8*>(bbase);
    acc = __builtin_amdgcn_mfma_f32_32x32x16_bf16(abias, Bb, acc, 0, 0, 0);
  }
  #pragma unroll
  for (int r = 0; r < 16; ++r) {
    int cl = (r & 3) + 8 * (r >> 2) + 4 * hi;
    out[(size_t)(M0 + cl) * O_ + o0 + lo] = acc[r];
  }
}

// ---------------------------------------------------------------------------
extern "C" void kernel_launch(void* const* d_in, const int* in_sizes, int n_in,
                              void* d_out, int out_size, void* d_ws, size_t ws_size,
                              hipStream_t stream)
{
  const float* x    = (const float*)d_in[0];
  const float* emb0 = (const float*)d_in[1];
  const float* emb1 = (const float*)d_in[2];
  const float* w1   = (const float*)d_in[3];
  const float* b1   = (const float*)d_in[4];
  const float* w2   = (const float*)d_in[5];
  const float* b2   = (const float*)d_in[6];
  const float* w3   = (const float*)d_in[7];
  const float* b3   = (const float*)d_in[8];
  const float* wp   = (const float*)d_in[9];
  const float* bp   = (const float*)d_in[10];
  float* out = (float*)d_out;
  float* ws  = (float*)d_ws;   // needs ~31.3 MB

  unsigned short* nvb   = (unsigned short*)(ws + NVB_OFF);
  float*          rsp   = ws + RSP_OFF;
  unsigned short* xsT   = (unsigned short*)(ws + XST_OFF);
  unsigned short* yT    = (unsigned short*)(ws + YT_OFF);
  unsigned short* xgall = (unsigned short*)(ws + XGALL_OFF);
  unsigned short* wpB   = (unsigned short*)(ws + WPB_OFF);
  unsigned short* emb1b = (unsigned short*)(ws + E1B_OFF);

  k01_fused<<<772, 256, 0, stream>>>(x, emb0, w1, b1, w2, b2, w3, b3,
                                     wp, bp, emb1, nvb, xgall, wpB, emb1b);
  p1_rowsum<<<1024, 256, 0, stream>>>(nvb, rsp);
  p2_scaleT<<<dim3(16,16), 256, 0, stream>>>(x, rsp, xsT);
  p3_spmm  <<<1024, 256, 0, stream>>>(nvb, xsT, yT);
  p4_xg2   <<<dim3(32,16), 256, 0, stream>>>(yT, rsp, xgall);
  k5_out   <<<512, 256, 0, stream>>>(xgall, emb1b, emb1, wpB, out);
}

// Round 12
// 172.635 us; speedup vs baseline: 1.4481x; 1.0277x over previous
//
#include <hip/hip_runtime.h>
#include <hip/hip_bf16.h>

// Problem constants (fixed by setup_inputs)
#define B_ 16
#define N_ 2048
#define C_ 64
#define E_ 16
#define O_ 64
#define H_ 16

typedef __attribute__((ext_vector_type(8)))  short short8;   // 8 bf16 (MFMA A/B frag)
typedef __attribute__((ext_vector_type(16))) float f32x16;   // MFMA C/D frag

// Workspace layout (float offsets). Total ~7,815,680 floats = 31.3 MB.
#define NVB_OFF   0u         // nodevec bf16 [B][N][E]        262144 f
#define RSP_OFF   262144u    // rowsum  f32  [4][B][N]        131072 f
#define XST_OFF   393216u    // xs^T bf16 [B][N/32][C][32]    1048576 f
#define YT_OFF    1441792u   // A@xs bf16 [4][B][C][N]        4194304 f
#define XGALL_OFF 5636096u   // xg bf16 [B][N][128] (x|xg2)   2097152 f
#define WPB_OFF   7733248u   // wpB bf16 frag-ordered         66048 f
#define E1B_OFF   7799296u   // emb1 bf16 [N][16]             16384 f

__device__ __forceinline__ unsigned short f2bf(float f) {
  union { float f; unsigned int u; } v; v.f = f;
  unsigned int r = v.u + 0x7FFFu + ((v.u >> 16) & 1u);   // RNE
  return (unsigned short)(r >> 16);
}
__device__ __forceinline__ float bf2f(unsigned short u) {
  union { unsigned int i; float f; } v; v.i = ((unsigned int)u) << 16;
  return v.f;
}

#define CVT_PK(dst, lo_, hi_) \
  asm("v_cvt_pk_bf16_f32 %0, %1, %2" : "=v"(dst) : "v"(lo_), "v"(hi_))
#define PL_SWAP(x_, y_) \
  asm("v_permlane32_swap_b32 %0, %1" : "+v"(x_), "+v"(y_))

// ---------------------------------------------------------------------------
// K01: fused prep + hypernet. Blocks 0..127: k1 (MLP + nodevec + x->bf16),
// LDS-staged coalesced x loads. Blocks 128..771: prep (wpB via LDS-staged
// coalesced wp reads; emb1b direct).
// ---------------------------------------------------------------------------
__global__ __launch_bounds__(256) void k01_fused(
    const float* __restrict__ x, const float* __restrict__ emb0,
    const float* __restrict__ w1, const float* __restrict__ b1,
    const float* __restrict__ w2, const float* __restrict__ b2,
    const float* __restrict__ w3, const float* __restrict__ b3,
    const float* __restrict__ wp, const float* __restrict__ bp,
    const float* __restrict__ emb1,
    unsigned short* __restrict__ nvb, unsigned short* __restrict__ xgall,
    unsigned short* __restrict__ wpB, unsigned short* __restrict__ emb1b)
{
  int tid = threadIdx.x;
  if (blockIdx.x >= 128) {
    // ---- prep work ----
    int bid = blockIdx.x - 128;          // 0..643
    int id  = bid * 256 + tid;
    if (id < 132096) {
      __shared__ float ls[8][68];        // padded: <=2-way bank aliasing
      int sub = (bid >> 1) & 1, kc = bid >> 2;
      const float* src = (kc < 128) ? (wp + (size_t)(kc * 16 + sub * 8) * 64)
                                    : (bp + (size_t)sub * 8 * 64);
      #pragma unroll
      for (int j = 0; j < 2; ++j) {
        int i2 = j * 256 + tid;          // 0..511, coalesced
        ls[i2 >> 6][i2 & 63] = src[i2];
      }
      __syncthreads();
      int t = tid & 7;
      int o = ((bid & 1) << 5) | (tid >> 3);
      wpB[id] = f2bf(ls[t][o]);
    } else {
      int id2 = id - 132096;             // < 32768
      emb1b[id2] = f2bf(emb1[id2]);
    }
    return;
  }

  // ---- k1 work ----
  __shared__ float xt[128][65];     // 33.3 KB staging, 65-pad: conflict-free
  __shared__ float w1s[C_*H_];
  __shared__ float b1s[H_], w2s[H_*2], b2s[2], w3s[2*E_], b3s[E_];
  for (int i = tid; i < C_*H_; i += 256) w1s[i] = w1[i];
  if (tid < H_)   b1s[tid] = b1[tid];
  if (tid < H_*2) w2s[tid] = w2[tid];
  if (tid < 2)    b2s[tid] = b2[tid];
  if (tid < 2*E_) w3s[tid] = w3[tid];
  if (tid < E_)   b3s[tid] = b3[tid];

  int base = blockIdx.x * 256;      // row base (b*N + n space)
  float xr[C_];
  #pragma unroll
  for (int ph = 0; ph < 2; ++ph) {
    const float4* src = reinterpret_cast<const float4*>(x + (size_t)(base + ph*128) * C_);
    #pragma unroll
    for (int j = 0; j < 8; ++j) {
      int i = j * 256 + tid;        // float4 index 0..2047
      float4 v = src[i];
      int row = i >> 4, c4 = (i & 15) * 4;
      xt[row][c4]   = v.x; xt[row][c4+1] = v.y;
      xt[row][c4+2] = v.z; xt[row][c4+3] = v.w;
    }
    __syncthreads();
    if ((tid >> 7) == ph) {
      int lr = tid & 127;
      #pragma unroll
      for (int j = 0; j < C_; ++j) xr[j] = xt[lr][j];
    }
    __syncthreads();
  }

  int idx = base + tid;  // b*N + n
  unsigned short xus[C_];
  #pragma unroll
  for (int c = 0; c < C_; ++c) xus[c] = f2bf(xr[c]);
  unsigned short* xo = xgall + (size_t)idx * 128;
  #pragma unroll
  for (int j = 0; j < 8; ++j)
    reinterpret_cast<uint4*>(xo)[j] = reinterpret_cast<uint4*>(xus)[j];

  float h1[H_];
  #pragma unroll
  for (int h = 0; h < H_; ++h) h1[h] = b1s[h];
  #pragma unroll 8
  for (int c = 0; c < C_; ++c) {
    float xv = xr[c];
    #pragma unroll
    for (int j = 0; j < 4; ++j) {
      float4 w = reinterpret_cast<const float4*>(&w1s[c*H_])[j];
      h1[4*j]   = fmaf(xv, w.x, h1[4*j]);
      h1[4*j+1] = fmaf(xv, w.y, h1[4*j+1]);
      h1[4*j+2] = fmaf(xv, w.z, h1[4*j+2]);
      h1[4*j+3] = fmaf(xv, w.w, h1[4*j+3]);
    }
  }
  #pragma unroll
  for (int h = 0; h < H_; ++h) h1[h] = 1.f / (1.f + __expf(-h1[h]));
  float a0 = b2s[0], a1 = b2s[1];
  #pragma unroll
  for (int h = 0; h < H_; ++h) {
    a0 = fmaf(h1[h], w2s[h*2],   a0);
    a1 = fmaf(h1[h], w2s[h*2+1], a1);
  }
  a0 = 1.f / (1.f + __expf(-a0));
  a1 = 1.f / (1.f + __expf(-a1));

  const float4* ep = reinterpret_cast<const float4*>(emb0 + (size_t)idx * E_);
  unsigned short us[E_];
  #pragma unroll
  for (int j = 0; j < 4; ++j) {
    float4 e = ep[j];
    int c = 4*j;
    us[c]   = f2bf(tanhf(e.x * (b3s[c]   + a0*w3s[c]   + a1*w3s[E_+c])));
    us[c+1] = f2bf(tanhf(e.y * (b3s[c+1] + a0*w3s[c+1] + a1*w3s[E_+c+1])));
    us[c+2] = f2bf(tanhf(e.z * (b3s[c+2] + a0*w3s[c+2] + a1*w3s[E_+c+2])));
    us[c+3] = f2bf(tanhf(e.w * (b3s[c+3] + a0*w3s[c+3] + a1*w3s[E_+c+3])));
  }
  *reinterpret_cast<short8*>(nvb + (size_t)idx * E_)     = *reinterpret_cast<short8*>(&us[0]);
  *reinterpret_cast<short8*>(nvb + (size_t)idx * E_ + 8) = *reinterpret_cast<short8*>(&us[8]);
}

// ---------------------------------------------------------------------------
// P1: rowsum partials via MFMA (swapped QK^T, lane owns n).
// grid 1024 (xcd-swizzled) x 256: 16 rb x 16 b x 4 part; m-quarter = 512.
// ---------------------------------------------------------------------------
__global__ __launch_bounds__(256, 4) void p1_rowsum(
    const unsigned short* __restrict__ nvb, float* __restrict__ rsp)
{
  int tid = threadIdx.x, lane = tid & 63, wid = tid >> 6;
  int lo = lane & 31, hi = lane >> 5;
  int orig = blockIdx.x;
  int eff = (orig & 7) * 128 + (orig >> 3);      // bijective XCD swizzle (1024 = 8*128)
  int rb = eff & 15, b = (eff >> 4) & 15, part = eff >> 8;   // part 0..3
  int N0 = rb * 128 + wid * 32;

  short8 bfrag = *reinterpret_cast<const short8*>(
      nvb + ((size_t)b * N_ + N0 + lo) * E_ + 8 * hi);
  f32x16 zero = {};
  float rs = 0.f;
  const unsigned short* abase =
      nvb + ((size_t)b * N_ + part * 512 + lo) * E_ + 8 * hi;
  #pragma unroll 2
  for (int mc = 0; mc < 16; ++mc) {
    short8 afrag = *reinterpret_cast<const short8*>(abase + (size_t)mc * 32 * E_);
    f32x16 p = __builtin_amdgcn_mfma_f32_32x32x16_bf16(afrag, bfrag, zero, 0, 0, 0);
    #pragma unroll
    for (int r = 0; r < 16; ++r) rs += fmaxf(p[r], 0.f);
  }
  rs += __shfl_xor(rs, 32, 64);
  if (lane < 32) rsp[((size_t)part * B_ + b) * N_ + N0 + lo] = rs;
}

// ---------------------------------------------------------------------------
// P2: xs^T tiled: xsT[b][m>>5][c][m&31] = bf16( d_m * x[b][m][c] ).
// grid (64,16) x 256 (4 blocks/CU); thread = (c, g); 8 m each, 16B store.
// ---------------------------------------------------------------------------
__global__ __launch_bounds__(256) void p2_scaleT(
    const float* __restrict__ x, const float* __restrict__ rsp,
    unsigned short* __restrict__ xsT)
{
  int tid = threadIdx.x;
  int c = tid & 63, g = tid >> 6;                // g 0..3
  int bx = blockIdx.x;                           // 0..63 (m-tile)
  int b  = blockIdx.y;
  int m0 = bx * 32 + g * 8;
  const float* rp = rsp + (size_t)b * N_;
  const size_t RST = (size_t)B_ * N_;            // part stride in rsp
  unsigned int pk[4];
  #pragma unroll
  for (int k = 0; k < 8; ++k) {
    int m = m0 + k;
    float s = rp[m] + rp[RST + m] + rp[2*RST + m] + rp[3*RST + m];
    float d = rsqrtf(s);
    float v = d * x[((size_t)b * N_ + m) * C_ + c];
    unsigned short us = f2bf(v);
    if (k & 1) pk[k >> 1] |= ((unsigned int)us) << 16;
    else       pk[k >> 1]  = us;
  }
  unsigned short* o = xsT + (((size_t)b * 64 + bx) * 64 + c) * 32 + g * 8;
  *reinterpret_cast<uint4*>(o) = *reinterpret_cast<uint4*>(&pk[0]);
}

// ---------------------------------------------------------------------------
// P3: y^T[part][b][c][n] = d_n * sum_{m in quarter} relu(nv_n.nv_m)*xs[m][c].
// d_n folded into the store (lane owns n). grid 1024 x 256, yT bf16.
// ---------------------------------------------------------------------------
__global__ __launch_bounds__(256, 4) void p3_spmm(
    const unsigned short* __restrict__ nvb, const unsigned short* __restrict__ xsT,
    const float* __restrict__ rsp, unsigned short* __restrict__ yT)
{
  int tid = threadIdx.x, lane = tid & 63, wid = tid >> 6;
  int lo = lane & 31, hi = lane >> 5;
  int orig = blockIdx.x;
  int eff = (orig & 7) * 128 + (orig >> 3);
  int rb = eff & 15, b = (eff >> 4) & 15, part = eff >> 8;   // part 0..3
  int N0 = rb * 128 + wid * 32;

  short8 bfrag = *reinterpret_cast<const short8*>(
      nvb + ((size_t)b * N_ + N0 + lo) * E_ + 8 * hi);
  f32x16 acc0 = {}, acc1 = {};
  f32x16 zero = {};
  const unsigned short* abase =
      nvb + ((size_t)b * N_ + part * 512 + lo) * E_ + 8 * hi;
  const unsigned short* xtile =
      xsT + (((size_t)b * 64 + part * 16) * 64) * 32 + lo * 32 + 8 * hi;

  #pragma unroll 2
  for (int mc = 0; mc < 16; ++mc) {
    short8 afrag = *reinterpret_cast<const short8*>(abase + (size_t)mc * 32 * E_);
    const unsigned short* xt = xtile + (size_t)mc * 2048;   // 64c * 32ms
    short8 x00 = *reinterpret_cast<const short8*>(xt);
    short8 x01 = *reinterpret_cast<const short8*>(xt + 16);
    short8 x10 = *reinterpret_cast<const short8*>(xt + 1024);
    short8 x11 = *reinterpret_cast<const short8*>(xt + 1024 + 16);

    f32x16 p = __builtin_amdgcn_mfma_f32_32x32x16_bf16(afrag, bfrag, zero, 0, 0, 0);
    float q[16];
    #pragma unroll
    for (int r = 0; r < 16; ++r) q[r] = fmaxf(p[r], 0.f);

    unsigned int A0, Bb0, C0, D0, A1, Bb1, C1, D1;
    CVT_PK(A0,  q[0],  q[1]);  CVT_PK(Bb0, q[2],  q[3]);
    CVT_PK(C0,  q[4],  q[5]);  CVT_PK(D0,  q[6],  q[7]);
    CVT_PK(A1,  q[8],  q[9]);  CVT_PK(Bb1, q[10], q[11]);
    CVT_PK(C1,  q[12], q[13]); CVT_PK(D1,  q[14], q[15]);
    PL_SWAP(A0, C0);  PL_SWAP(Bb0, D0);
    PL_SWAP(A1, C1);  PL_SWAP(Bb1, D1);

    union { unsigned int u[4]; short8 s; } f0, f1;
    f0.u[0] = A0; f0.u[1] = Bb0; f0.u[2] = C0; f0.u[3] = D0;
    f1.u[0] = A1; f1.u[1] = Bb1; f1.u[2] = C1; f1.u[3] = D1;

    acc0 = __builtin_amdgcn_mfma_f32_32x32x16_bf16(x00, f0.s, acc0, 0, 0, 0);
    acc0 = __builtin_amdgcn_mfma_f32_32x32x16_bf16(x01, f1.s, acc0, 0, 0, 0);
    acc1 = __builtin_amdgcn_mfma_f32_32x32x16_bf16(x10, f0.s, acc1, 0, 0, 0);
    acc1 = __builtin_amdgcn_mfma_f32_32x32x16_bf16(x11, f1.s, acc1, 0, 0, 0);
  }

  // d_n for this lane's column
  const size_t RST = (size_t)B_ * N_;
  const float* rpn = rsp + (size_t)b * N_ + N0 + lo;
  float dn = rsqrtf(rpn[0] + rpn[RST] + rpn[2*RST] + rpn[3*RST]);

  unsigned short* yb = yT + ((size_t)part * B_ + b) * C_ * N_;
  #pragma unroll
  for (int r = 0; r < 16; ++r) {
    int cl = (r & 3) + 8 * (r >> 2) + 4 * hi;       // verified C/D row mapping
    yb[(size_t)cl * N_ + N0 + lo]        = f2bf(dn * acc0[r]);
    yb[(size_t)(cl + 32) * N_ + N0 + lo] = f2bf(dn * acc1[r]);
  }
}

// ---------------------------------------------------------------------------
// P4: xg2 = sum of 4 bf16 yT parts -> xgall[:,64:128] via LDS transpose.
// grid (32,16) x 256.
// ---------------------------------------------------------------------------
__global__ __launch_bounds__(256) void p4_xg2(
    const unsigned short* __restrict__ yT, unsigned short* __restrict__ xgall)
{
  __shared__ unsigned short tile[64][72];   // 72: rows 144B (16B-aligned)
  int tid = threadIdx.x;
  int nl = tid & 63, cg = tid >> 6;         // cg 0..3, 16 c each
  int n0 = blockIdx.x * 64, b = blockIdx.y;
  int n = n0 + nl;
  const unsigned short* y0 = yT + (size_t)b * C_ * N_;
  const size_t PST = (size_t)B_ * C_ * N_;  // part stride (ushorts)
  #pragma unroll
  for (int cc = 0; cc < 16; cc += 2) {
    int c = cg * 16 + cc;
    size_t o0 = (size_t)c * N_ + n, o1 = (size_t)(c+1) * N_ + n;
    float v0 = bf2f(y0[o0]) + bf2f(y0[PST + o0]) + bf2f(y0[2*PST + o0]) + bf2f(y0[3*PST + o0]);
    float v1 = bf2f(y0[o1]) + bf2f(y0[PST + o1]) + bf2f(y0[2*PST + o1]) + bf2f(y0[3*PST + o1]);
    unsigned int pk = (unsigned int)f2bf(v0) | ((unsigned int)f2bf(v1) << 16);
    *reinterpret_cast<unsigned int*>(&tile[nl][c]) = pk;
  }
  __syncthreads();
  int q = tid & 3, j = tid >> 2;            // row j 0..63, quarter q
  uint4 va = *reinterpret_cast<const uint4*>(&tile[j][q*16]);
  uint4 vb = *reinterpret_cast<const uint4*>(&tile[j][q*16 + 8]);
  unsigned short* o = xgall + ((size_t)b * N_ + n0 + j) * 128 + 64 + q * 16;
  *reinterpret_cast<uint4*>(o)     = va;
  *reinterpret_cast<uint4*>(o + 8) = vb;
}

// ---------------------------------------------------------------------------
// K5: out[bn,o] = sum_d emb1[n,d] * (sum_ki xg[bn,ki] wp[d,ki,o]) + bias
// via bf16 MFMA, d processed in PAIRS (4 independent MFMA chains for ILP).
// grid 512 x 256 (2048 waves).
// ---------------------------------------------------------------------------
__global__ __launch_bounds__(256) void k5_out(
    const unsigned short* __restrict__ xgall, const unsigned short* __restrict__ emb1b,
    const float* __restrict__ emb1, const unsigned short* __restrict__ wpB,
    float* __restrict__ out)
{
  int tid = threadIdx.x, lane = tid & 63, wid = tid >> 6;
  int lo = lane & 31, hi = lane >> 5;
  int gw = blockIdx.x * 4 + wid;          // 0..2047
  int mt = gw >> 1;                       // M-tile 0..1023
  int o0 = (gw & 1) * 32;
  int M0 = mt * 32;                       // bn base (single b per tile)
  int n0 = M0 & (N_ - 1);

  const unsigned short* arow = xgall + (size_t)(M0 + lo) * 128 + 8 * hi;
  short8 a[8];
  #pragma unroll
  for (int c8 = 0; c8 < 8; ++c8)
    a[c8] = *reinterpret_cast<const short8*>(arow + c8 * 16);
  short8 abias = *reinterpret_cast<const short8*>(
      emb1b + (size_t)(n0 + lo) * E_ + 8 * hi);

  f32x16 acc = {};
  f32x16 kzero = {};

  int nr[16];
  #pragma unroll
  for (int r = 0; r < 16; ++r) nr[r] = n0 + (r & 3) + 8 * (r >> 2) + 4 * hi;

  #pragma unroll 2
  for (int dg = 0; dg < 8; ++dg) {        // d-pair (d = 2dg, 2dg+1)
    float2 e2[16];
    #pragma unroll
    for (int r = 0; r < 16; ++r)
      e2[r] = *reinterpret_cast<const float2*>(emb1 + (size_t)nr[r] * E_ + dg * 2);
    const unsigned short* bb0 = wpB + ((size_t)(dg * 32      + hi) * 64 + o0 + lo) * 8;
    const unsigned short* bb1 = wpB + ((size_t)(dg * 32 + 16 + hi) * 64 + o0 + lo) * 8;
    f32x16 t0a = kzero, t1a = kzero, t0b = kzero, t1b = kzero;
    #pragma unroll
    for (int c8 = 0; c8 < 8; c8 += 2) {
      short8 B0a = *reinterpret_cast<const short8*>(bb0 + (size_t)(c8    ) * 1024);
      short8 B1a = *reinterpret_cast<const short8*>(bb0 + (size_t)(c8 + 1) * 1024);
      short8 B0b = *reinterpret_cast<const short8*>(bb1 + (size_t)(c8    ) * 1024);
      short8 B1b = *reinterpret_cast<const short8*>(bb1 + (size_t)(c8 + 1) * 1024);
      t0a = __builtin_amdgcn_mfma_f32_32x32x16_bf16(a[c8],     B0a, t0a, 0, 0, 0);
      t1a = __builtin_amdgcn_mfma_f32_32x32x16_bf16(a[c8 + 1], B1a, t1a, 0, 0, 0);
      t0b = __builtin_amdgcn_mfma_f32_32x32x16_bf16(a[c8],     B0b, t0b, 0, 0, 0);
      t1b = __builtin_amdgcn_mfma_f32_32x32x16_bf16(a[c8 + 1], B1b, t1b, 0, 0, 0);
    }
    #pragma unroll
    for (int r = 0; r < 16; ++r)
      acc[r] = fmaf(e2[r].x, t0a[r] + t1a[r],
               fmaf(e2[r].y, t0b[r] + t1b[r], acc[r]));
  }
  // bias: one MFMA chunk (kc = 128)
  {
    const unsigned short* bbase = wpB + ((size_t)(256 + hi) * 64 + o0 + lo) * 8;
    short8 Bb = *reinterpret_cast<const short8*>(bbase);
    acc = __builtin_amdgcn_mfma_f32_32x32x16_bf16(abias, Bb, acc, 0, 0, 0);
  }
  #pragma unroll
  for (int r = 0; r < 16; ++r) {
    int cl = (r & 3) + 8 * (r >> 2) + 4 * hi;
    out[(size_t)(M0 + cl) * O_ + o0 + lo] = acc[r];
  }
}

// ---------------------------------------------------------------------------
extern "C" void kernel_launch(void* const* d_in, const int* in_sizes, int n_in,
                              void* d_out, int out_size, void* d_ws, size_t ws_size,
                              hipStream_t stream)
{
  const float* x    = (const float*)d_in[0];
  const float* emb0 = (const float*)d_in[1];
  const float* emb1 = (const float*)d_in[2];
  const float* w1   = (const float*)d_in[3];
  const float* b1   = (const float*)d_in[4];
  const float* w2   = (const float*)d_in[5];
  const float* b2   = (const float*)d_in[6];
  const float* w3   = (const float*)d_in[7];
  const float* b3   = (const float*)d_in[8];
  const float* wp   = (const float*)d_in[9];
  const float* bp   = (const float*)d_in[10];
  float* out = (float*)d_out;
  float* ws  = (float*)d_ws;   // needs ~31.3 MB

  unsigned short* nvb   = (unsigned short*)(ws + NVB_OFF);
  float*          rsp   = ws + RSP_OFF;
  unsigned short* xsT   = (unsigned short*)(ws + XST_OFF);
  unsigned short* yT    = (unsigned short*)(ws + YT_OFF);
  unsigned short* xgall = (unsigned short*)(ws + XGALL_OFF);
  unsigned short* wpB   = (unsigned short*)(ws + WPB_OFF);
  unsigned short* emb1b = (unsigned short*)(ws + E1B_OFF);

  k01_fused<<<772, 256, 0, stream>>>(x, emb0, w1, b1, w2, b2, w3, b3,
                                     wp, bp, emb1, nvb, xgall, wpB, emb1b);
  p1_rowsum<<<1024, 256, 0, stream>>>(nvb, rsp);
  p2_scaleT<<<dim3(64,16), 256, 0, stream>>>(x, rsp, xsT);
  p3_spmm  <<<1024, 256, 0, stream>>>(nvb, xsT, rsp, yT);
  p4_xg2   <<<dim3(32,16), 256, 0, stream>>>(yT, xgall);
  k5_out   <<<512, 256, 0, stream>>>(xgall, emb1b, emb1, wpB, out);
}